// Round 20
// baseline (198.242 us; speedup 1.0000x reference)
//
#include <hip/hip_runtime.h>
#include <stdint.h>

typedef unsigned short u16;
typedef __attribute__((ext_vector_type(4))) float f32x4;
typedef __attribute__((ext_vector_type(8))) short bfrag;

static __device__ __forceinline__ u16 f2bf(float f) {  // RNE
  union { float f; uint32_t u; } v; v.f = f;
  return (u16)((v.u + 0x7fffu + ((v.u >> 16) & 1u)) >> 16);
}
static __device__ __forceinline__ uint32_t cvtpk(float lo, float hi) {
  uint32_t r;
  asm("v_cvt_pk_bf16_f32 %0, %1, %2" : "=v"(r) : "v"(lo), "v"(hi));
  return r;
}
static __device__ __forceinline__ uint32_t pk2bf(float lo, float hi) {
  union { float f; uint32_t u; } a, b; a.f = lo; b.f = hi;
  return __builtin_amdgcn_perm(b.u + 0x8000u, a.u + 0x8000u, 0x07060302u);
}
// single-instruction 2^x (v_exp_f32 is natively base-2)
static __device__ __forceinline__ float fexp2(float x) {
  float r;
  asm("v_exp_f32 %0, %1" : "=v"(r) : "v"(x));
  return r;
}

#define GLOAD16(gp, lp)                                              \
  __builtin_amdgcn_global_load_lds(                                  \
      (const __attribute__((address_space(1))) uint32_t*)(gp),       \
      (__attribute__((address_space(3))) uint32_t*)(lp), 16, 0, 0)

// ---------------- pack W: [1024][64] f32 slice -> Wt[h*64+e][k] bf16
__global__ __launch_bounds__(256) void pack_w_hde(const float* __restrict__ W,
                                                  u16* __restrict__ Wt) {
  __shared__ float tile[64][65];
  const int h = blockIdx.y, k0 = blockIdx.x * 64;
  const int tid = threadIdx.x;
#pragma unroll
  for (int j = 0; j < 4; ++j) {
    int idx = tid + j * 256;
    int rr = idx >> 4, c4 = (idx & 15) * 4;
    const float4 v = *(const float4*)(W + (size_t)h * 65536 + (size_t)(k0 + rr) * 64 + c4);
    tile[rr][c4 + 0] = v.x; tile[rr][c4 + 1] = v.y;
    tile[rr][c4 + 2] = v.z; tile[rr][c4 + 3] = v.w;
  }
  __syncthreads();
#pragma unroll
  for (int j = 0; j < 4; ++j) {
    int idx = tid + j * 256;
    int ee = idx >> 4, c4 = (idx & 15) * 4;
    uint2 u;
    u.x = f2bf(tile[c4 + 0][ee]) | ((uint32_t)f2bf(tile[c4 + 1][ee]) << 16);
    u.y = f2bf(tile[c4 + 2][ee]) | ((uint32_t)f2bf(tile[c4 + 3][ee]) << 16);
    *(uint2*)(Wt + (size_t)(h * 64 + ee) * 1024 + k0 + c4) = u;
  }
}

// ---------------- transpose Wo: [1024][1024] f32 -> bf16, out[n][k] = Wo[k][n]
__global__ __launch_bounds__(256) void transpose_w(const float* __restrict__ W,
                                                   u16* __restrict__ Wt) {
  __shared__ float tile[64][65];
  const int k0 = blockIdx.x * 64, n0 = blockIdx.y * 64;
  const int tid = threadIdx.x;
#pragma unroll
  for (int j = 0; j < 4; ++j) {
    int idx = tid + j * 256;
    int rr = idx >> 4, c4 = (idx & 15) * 4;
    const float4 v = *(const float4*)(W + (size_t)(k0 + rr) * 1024 + n0 + c4);
    tile[rr][c4 + 0] = v.x; tile[rr][c4 + 1] = v.y;
    tile[rr][c4 + 2] = v.z; tile[rr][c4 + 3] = v.w;
  }
  __syncthreads();
#pragma unroll
  for (int j = 0; j < 4; ++j) {
    int idx = tid + j * 256;
    int ee = idx >> 4, c4 = (idx & 15) * 4;
    uint2 u;
    u.x = f2bf(tile[c4 + 0][ee]) | ((uint32_t)f2bf(tile[c4 + 1][ee]) << 16);
    u.y = f2bf(tile[c4 + 2][ee]) | ((uint32_t)f2bf(tile[c4 + 3][ee]) << 16);
    *(uint2*)(Wt + (size_t)(n0 + ee) * 1024 + k0 + c4) = u;
  }
}

// ---------------- elementwise f32 -> bf16 convert of Q/K/V activations
__global__ __launch_bounds__(256) void conv_bf16(const float* __restrict__ q,
                                                 const float* __restrict__ k,
                                                 const float* __restrict__ v,
                                                 u16* __restrict__ oq,
                                                 u16* __restrict__ ok,
                                                 u16* __restrict__ ov) {
  const float* in = (blockIdx.y == 0) ? q : (blockIdx.y == 1) ? k : v;
  u16* out = (blockIdx.y == 0) ? oq : (blockIdx.y == 1) ? ok : ov;
  const size_t i = ((size_t)blockIdx.x * 256 + threadIdx.x) * 8;
  const float4 f0 = *(const float4*)(in + i);
  const float4 f1 = *(const float4*)(in + i + 4);
  uint4 u;
  u.x = pk2bf(f0.x, f0.y); u.y = pk2bf(f0.z, f0.w);
  u.z = pk2bf(f1.x, f1.y); u.w = pk2bf(f1.z, f1.w);
  *(uint4*)(out + i) = u;
}

// ---------------- fast-path QKV GEMM: A bf16 (pre-converted) x Wqkv^T + bias
// m97 structure: BOTH operands via global_load_lds (source-XOR-swizzled),
// zero staging VALU. 2-phase, 1 barrier/K-step. Q scaled to log2 domain.
__global__ __launch_bounds__(256) void gemm_qkvb(
    const u16* __restrict__ cq, const u16* __restrict__ ck,
    const u16* __restrict__ cv, const u16* __restrict__ Bt,
    const float* __restrict__ bq, const float* __restrict__ bk,
    const float* __restrict__ bv,
    u16* __restrict__ Qb, u16* __restrict__ Kb, u16* __restrict__ Vt) {
  __shared__ u16 As[2][128 * 32];
  __shared__ u16 Bs[2][128 * 32];
  const int tid = threadIdx.x;
  const int n = blockIdx.x;
  const int xcd = n & 7, j = n >> 3;
  const int mb = xcd * 8 + (j & 7);   // 0..63
  const int nb = j >> 3;              // 0..23
  const int chunk = nb >> 3;          // 0:Q 1:K 2:V
  const u16* Abf = (chunk == 0) ? cq : (chunk == 1) ? ck : cv;
  const int wid = tid >> 6, lane = tid & 63;
  const int wr = wid >> 1, wc = wid & 1;
  const int g = lane >> 4, l15 = lane & 15;
  f32x4 acc[4][4] = {};

  const int bsrc = ((lane & 3) ^ ((lane >> 3) & 3)) * 8;
  const int swzr = (l15 >> 1) & 3;
  const u16* Bg = Bt + (size_t)(nb * 128 + 2 * wid * 16 + (lane >> 2)) * 1024 + bsrc;
  const u16* Ag = Abf + (size_t)(mb * 128 + 2 * wid * 16 + (lane >> 2)) * 1024 + bsrc;

#pragma unroll
  for (int c = 0; c < 2; ++c) {
    GLOAD16(Ag + (size_t)c * 16 * 1024, &As[0][2 * wid * 512 + c * 512]);
    GLOAD16(Bg + (size_t)c * 16 * 1024, &Bs[0][2 * wid * 512 + c * 512]);
  }
  __syncthreads();
  int cur = 0;
  for (int kk = 0; kk < 32; ++kk) {
    if (kk < 31) {
      const int kn = (kk + 1) * 32;
#pragma unroll
      for (int c = 0; c < 2; ++c) {
        GLOAD16(Ag + (size_t)c * 16 * 1024 + kn, &As[cur ^ 1][2 * wid * 512 + c * 512]);
        GLOAD16(Bg + (size_t)c * 16 * 1024 + kn, &Bs[cur ^ 1][2 * wid * 512 + c * 512]);
      }
    }
    bfrag a[4], b[4];
#pragma unroll
    for (int m = 0; m < 4; ++m)
      a[m] = __builtin_bit_cast(bfrag,
          *(const uint4*)&As[cur][(wr * 64 + m * 16 + l15) * 32 + ((g ^ swzr)) * 8]);
#pragma unroll
    for (int nn = 0; nn < 4; ++nn)
      b[nn] = __builtin_bit_cast(bfrag,
          *(const uint4*)&Bs[cur][(wc * 64 + nn * 16 + l15) * 32 + ((g ^ swzr)) * 8]);
    __builtin_amdgcn_s_setprio(1);
#pragma unroll
    for (int m = 0; m < 4; ++m)
#pragma unroll
      for (int nn = 0; nn < 4; ++nn)
        acc[m][nn] = __builtin_amdgcn_mfma_f32_16x16x32_bf16(a[m], b[nn], acc[m][nn], 0, 0, 0);
    __builtin_amdgcn_s_setprio(0);
    if (kk < 31) { __syncthreads(); cur ^= 1; }
  }

  const int row0 = mb * 128 + wr * 64 + g * 4;
  const int cc0 = (nb & 7) * 128 + wc * 64 + l15;
  const float* bias = (chunk == 0) ? bq : (chunk == 1) ? bk : bv;
  const float qs = (chunk == 0) ? 0.125f * 1.44269504f : 1.0f;  // log2 domain
#pragma unroll
  for (int m = 0; m < 4; ++m) {
#pragma unroll
    for (int nn = 0; nn < 4; ++nn) {
      const int row = row0 + m * 16;
      const int cc = cc0 + nn * 16;
      const float bcv = bias[cc];
      if (chunk < 2) {
        u16* dst = (chunk == 0) ? Qb : Kb;
#pragma unroll
        for (int r = 0; r < 4; ++r)
          dst[(size_t)(row + r) * 1024 + cc] = f2bf((acc[m][nn][r] + bcv) * qs);
      } else {
        u16 w[4];
#pragma unroll
        for (int r = 0; r < 4; ++r) w[r] = f2bf(acc[m][nn][r] + bcv);
        const size_t dst =
            ((size_t)((row >> 11) * 16 + (cc >> 6)) * 64 + (cc & 63)) * 2048 + (row & 2047);
        *(uint2*)(Vt + dst) = *(const uint2*)w;
      }
    }
  }
}

// ---------------- fallback QKV GEMM (R19): f32 A reg-staged each step
__global__ __launch_bounds__(256) void gemm_qkv(
    const float* __restrict__ Aq, const float* __restrict__ Ak,
    const float* __restrict__ Avv, const u16* __restrict__ Bt,
    const float* __restrict__ bq, const float* __restrict__ bk,
    const float* __restrict__ bv,
    u16* __restrict__ Qb, u16* __restrict__ Kb, u16* __restrict__ Vt) {
  __shared__ u16 As[2][128 * 32];
  __shared__ u16 Bs[2][128 * 32];
  const int tid = threadIdx.x;
  const int n = blockIdx.x;
  const int xcd = n & 7, j = n >> 3;
  const int mb = xcd * 8 + (j & 7);
  const int nb = j >> 3;
  const int chunk = nb >> 3;
  const float* Af = (chunk == 0) ? Aq : (chunk == 1) ? Ak : Avv;
  const int wid = tid >> 6, lane = tid & 63;
  const int wr = wid >> 1, wc = wid & 1;
  const int g = lane >> 4, l15 = lane & 15;
  f32x4 acc[4][4] = {};

  const int bsrc = ((lane & 3) ^ ((lane >> 3) & 3)) * 8;
  const u16* Bg = Bt + (size_t)(nb * 128 + 2 * wid * 16 + (lane >> 2)) * 1024 + bsrc;
  const float* Ap = Af + (size_t)(mb * 128 + (tid >> 2)) * 1024 + (tid & 3) * 8;
  const int arow = tid >> 2;
  const int acs = (((tid & 3) ^ ((tid >> 3) & 3))) * 8;
  const int swzr = (l15 >> 1) & 3;

  float4 fa[2][2];
#pragma unroll
  for (int c = 0; c < 2; ++c) {
    fa[c][0] = *(const float4*)(Ap + (size_t)c * 64 * 1024);
    fa[c][1] = *(const float4*)(Ap + (size_t)c * 64 * 1024 + 4);
  }
#pragma unroll
  for (int c = 0; c < 2; ++c)
    GLOAD16(Bg + (size_t)c * 16 * 1024, &Bs[0][2 * wid * 512 + c * 512]);
#pragma unroll
  for (int c = 0; c < 2; ++c) {
    uint4 u;
    u.x = pk2bf(fa[c][0].x, fa[c][0].y); u.y = pk2bf(fa[c][0].z, fa[c][0].w);
    u.z = pk2bf(fa[c][1].x, fa[c][1].y); u.w = pk2bf(fa[c][1].z, fa[c][1].w);
    *(uint4*)&As[0][(arow + c * 64) * 32 + acs] = u;
  }
  __syncthreads();
  int cur = 0;
  for (int kk = 0; kk < 32; ++kk) {
    if (kk < 31) {
      const int kn = (kk + 1) * 32;
#pragma unroll
      for (int c = 0; c < 2; ++c) {
        fa[c][0] = *(const float4*)(Ap + (size_t)c * 64 * 1024 + kn);
        fa[c][1] = *(const float4*)(Ap + (size_t)c * 64 * 1024 + kn + 4);
      }
#pragma unroll
      for (int c = 0; c < 2; ++c)
        GLOAD16(Bg + (size_t)c * 16 * 1024 + kn, &Bs[cur ^ 1][2 * wid * 512 + c * 512]);
    }
    bfrag a[4], b[4];
#pragma unroll
    for (int m = 0; m < 4; ++m)
      a[m] = __builtin_bit_cast(bfrag,
          *(const uint4*)&As[cur][(wr * 64 + m * 16 + l15) * 32 + ((g ^ swzr)) * 8]);
#pragma unroll
    for (int nn = 0; nn < 4; ++nn)
      b[nn] = __builtin_bit_cast(bfrag,
          *(const uint4*)&Bs[cur][(wc * 64 + nn * 16 + l15) * 32 + ((g ^ swzr)) * 8]);
    __builtin_amdgcn_s_setprio(1);
#pragma unroll
    for (int m = 0; m < 4; ++m)
#pragma unroll
      for (int nn = 0; nn < 4; ++nn)
        acc[m][nn] = __builtin_amdgcn_mfma_f32_16x16x32_bf16(a[m], b[nn], acc[m][nn], 0, 0, 0);
    __builtin_amdgcn_s_setprio(0);
    if (kk < 31) {
#pragma unroll
      for (int c = 0; c < 2; ++c) {
        uint4 u;
        u.x = pk2bf(fa[c][0].x, fa[c][0].y); u.y = pk2bf(fa[c][0].z, fa[c][0].w);
        u.z = pk2bf(fa[c][1].x, fa[c][1].y); u.w = pk2bf(fa[c][1].z, fa[c][1].w);
        *(uint4*)&As[cur ^ 1][(arow + c * 64) * 32 + acs] = u;
      }
      __syncthreads();
      cur ^= 1;
    }
  }

  const int row0 = mb * 128 + wr * 64 + g * 4;
  const int cc0 = (nb & 7) * 128 + wc * 64 + l15;
  const float* bias = (chunk == 0) ? bq : (chunk == 1) ? bk : bv;
  const float qs = (chunk == 0) ? 0.125f * 1.44269504f : 1.0f;  // log2 domain
#pragma unroll
  for (int m = 0; m < 4; ++m) {
#pragma unroll
    for (int nn = 0; nn < 4; ++nn) {
      const int row = row0 + m * 16;
      const int cc = cc0 + nn * 16;
      const float bcv = bias[cc];
      if (chunk < 2) {
        u16* dst = (chunk == 0) ? Qb : Kb;
#pragma unroll
        for (int r = 0; r < 4; ++r)
          dst[(size_t)(row + r) * 1024 + cc] = f2bf((acc[m][nn][r] + bcv) * qs);
      } else {
        u16 w[4];
#pragma unroll
        for (int r = 0; r < 4; ++r) w[r] = f2bf(acc[m][nn][r] + bcv);
        const size_t dst =
            ((size_t)((row >> 11) * 16 + (cc >> 6)) * 64 + (cc & 63)) * 2048 + (row & 2047);
        *(uint2*)(Vt + dst) = *(const uint2*)w;
      }
    }
  }
}

// ---------------- O-projection GEMM (R13, unchanged)
__global__ __launch_bounds__(256) void gemm_o(const u16* __restrict__ Abf,
                                              const u16* __restrict__ Bt,
                                              const float* __restrict__ bo,
                                              float* __restrict__ Of) {
  __shared__ u16 As[2][128 * 32];
  __shared__ u16 Bs[2][128 * 32];
  const int tid = threadIdx.x;
  const int n = blockIdx.x;
  const int xcd = n & 7, j = n >> 3;
  const int mb = xcd * 8 + (j & 7);
  const int nb = j >> 3;
  const int wid = tid >> 6, lane = tid & 63;
  const int wr = wid >> 1, wc = wid & 1;
  const int g = lane >> 4, l15 = lane & 15;
  f32x4 acc[4][4] = {};

  const int bsrc = ((lane & 3) ^ ((lane >> 3) & 3)) * 8;
  const int swzr = (l15 >> 1) & 3;
  const u16* Bg = Bt + (size_t)(nb * 128 + 2 * wid * 16 + (lane >> 2)) * 1024 + bsrc;
  const u16* Ag = Abf + (size_t)(mb * 128 + 2 * wid * 16 + (lane >> 2)) * 1024 + bsrc;

#pragma unroll
  for (int c = 0; c < 2; ++c) {
    GLOAD16(Ag + (size_t)c * 16 * 1024, &As[0][2 * wid * 512 + c * 512]);
    GLOAD16(Bg + (size_t)c * 16 * 1024, &Bs[0][2 * wid * 512 + c * 512]);
  }
  __syncthreads();
  int cur = 0;
  for (int kk = 0; kk < 32; ++kk) {
    if (kk < 31) {
      const int kn = (kk + 1) * 32;
#pragma unroll
      for (int c = 0; c < 2; ++c) {
        GLOAD16(Ag + (size_t)c * 16 * 1024 + kn, &As[cur ^ 1][2 * wid * 512 + c * 512]);
        GLOAD16(Bg + (size_t)c * 16 * 1024 + kn, &Bs[cur ^ 1][2 * wid * 512 + c * 512]);
      }
    }
    bfrag a[4], b[4];
#pragma unroll
    for (int m = 0; m < 4; ++m)
      a[m] = __builtin_bit_cast(bfrag,
          *(const uint4*)&As[cur][(wr * 64 + m * 16 + l15) * 32 + ((g ^ swzr)) * 8]);
#pragma unroll
    for (int nn = 0; nn < 4; ++nn)
      b[nn] = __builtin_bit_cast(bfrag,
          *(const uint4*)&Bs[cur][(wc * 64 + nn * 16 + l15) * 32 + ((g ^ swzr)) * 8]);
    __builtin_amdgcn_s_setprio(1);
#pragma unroll
    for (int m = 0; m < 4; ++m)
#pragma unroll
      for (int nn = 0; nn < 4; ++nn)
        acc[m][nn] = __builtin_amdgcn_mfma_f32_16x16x32_bf16(a[m], b[nn], acc[m][nn], 0, 0, 0);
    __builtin_amdgcn_s_setprio(0);
    if (kk < 31) { __syncthreads(); cur ^= 1; }
  }

  const int row0 = mb * 128 + wr * 64 + g * 4;
  const int col0 = nb * 128 + wc * 64 + l15;
#pragma unroll
  for (int m = 0; m < 4; ++m)
#pragma unroll
    for (int nn = 0; nn < 4; ++nn) {
      const int row = row0 + m * 16, col = col0 + nn * 16;
      const float bcv = bo[col];
#pragma unroll
      for (int r = 0; r < 4; ++r)
        Of[(size_t)(row + r) * 1024 + col] = acc[m][nn][r] + bcv;
    }
}

// ---------------- fused causal flash attention — fixed-max softmax with
// single-instruction v_exp_f32 (base-2). Scores arrive in log2 domain. (R19)
__global__ __launch_bounds__(512) void attn_fused(const u16* __restrict__ Qb,
                                                  const u16* __restrict__ Kb,
                                                  const u16* __restrict__ Vtg,
                                                  u16* __restrict__ Ob) {
  __shared__ u16 KV[2][2][4096];
  const int tid = threadIdx.x;
  const int wid = tid >> 6, lane = tid & 63;
  const int g = lane >> 4, l15 = lane & 15;
  const int n = blockIdx.x;
  const int half = n >> 8, idx = n & 255;
  const int xcd = idx & 7;
  const int bh = xcd * 8 + ((idx >> 3) & 7);
  const int grp = idx >> 6;
  const int u = half ? grp : (7 - grp);
  const int t = u * 8 + wid;
  const int b = bh >> 4, h = bh & 15;
  const size_t baserow = (size_t)b * 2048;
  const u16* Qg = Qb + baserow * 1024 + h * 64;
  const u16* Kg = Kb + baserow * 1024 + h * 64;
  const u16* Vg = Vtg + (size_t)bh * 64 * 2048;
  u16* Og = Ob + baserow * 1024 + h * 64;

  const int q0 = t * 32;
  const int qrow = q0 + l15;
  const int mysteps = (q0 >> 6) + 1;
  const int smax = 4 * u + 4;
  const float M2 = 6.0f;

  const int sr = tid >> 3;
  const int scc = (tid & 7) ^ (sr & 7);
  const u16* Kst = Kg + (size_t)sr * 1024 + scc * 8;
  const u16* Vst = Vg + (size_t)sr * 2048 + scc * 8;

  bfrag qa[2][2];
#pragma unroll
  for (int qf = 0; qf < 2; ++qf)
#pragma unroll
    for (int kh = 0; kh < 2; ++kh)
      qa[qf][kh] = __builtin_bit_cast(bfrag,
          *(const uint4*)(Qg + (size_t)(q0 + qf * 16 + l15) * 1024 + kh * 32 + g * 8));

  f32x4 accT[2][4] = {};
  float Ll[2] = {0.f, 0.f};

  const int s0lane = ((g & 1) << 5) | l15;
  const int s1lane = s0lane + 16;
  const bool ghi = (g >= 2);
  const int swz = l15 & 7;

  GLOAD16(Kst, &KV[0][0][wid * 512]);
  GLOAD16(Vst, &KV[0][1][wid * 512]);
  __syncthreads();

  for (int s = 0; s < smax; ++s) {
    const int cb = s & 1;
    if (s + 1 < smax) {
      const size_t kn = (size_t)(s + 1) << 6;
      GLOAD16(Kst + kn * 1024, &KV[cb ^ 1][0][wid * 512]);
      GLOAD16(Vst + kn, &KV[cb ^ 1][1][wid * 512]);
    }
    if (s < mysteps) {
      const int kv0 = s << 6;
      const bool diag = (s == mysteps - 1);
      const u16* KB = &KV[cb][0][0];
      const u16* VB = &KV[cb][1][0];

      bfrag kb[2][4];
#pragma unroll
      for (int tt = 0; tt < 4; ++tt)
#pragma unroll
        for (int kh = 0; kh < 2; ++kh)
          kb[kh][tt] = __builtin_bit_cast(bfrag,
              *(const uint4*)&KB[(tt * 16 + l15) * 64 + (((kh << 2) | g) ^ swz) * 8]);

      f32x4 sc[2][4];
      __builtin_amdgcn_s_setprio(1);
#pragma unroll
      for (int qf = 0; qf < 2; ++qf)
#pragma unroll
        for (int tt = 0; tt < 4; ++tt) {
          f32x4 z = {0.f, 0.f, 0.f, 0.f};
          z = __builtin_amdgcn_mfma_f32_16x16x32_bf16(kb[0][tt], qa[qf][0], z, 0, 0, 0);
          z = __builtin_amdgcn_mfma_f32_16x16x32_bf16(kb[1][tt], qa[qf][1], z, 0, 0, 0);
          sc[qf][tt] = z;
        }
      __builtin_amdgcn_s_setprio(0);

      bfrag vb[2][4];
#pragma unroll
      for (int et = 0; et < 4; ++et)
#pragma unroll
        for (int kcb = 0; kcb < 2; ++kcb)
          vb[kcb][et] = __builtin_bit_cast(bfrag,
              *(const uint4*)&VB[(et * 16 + l15) * 64 + (((kcb << 2) | g) ^ swz) * 8]);

#pragma unroll
      for (int qf = 0; qf < 2; ++qf) {
        if (diag) {
          const int qq = qrow + qf * 16;
#pragma unroll
          for (int tt = 0; tt < 4; ++tt) {
            const int kvb = kv0 + tt * 16 + g * 4;
#pragma unroll
            for (int r = 0; r < 4; ++r)
              sc[qf][tt][r] = (kvb + r <= qq) ? sc[qf][tt][r] : -100.0f;
          }
        }
        uint32_t pk[4][2];
        float ss = 0.f;
#pragma unroll
        for (int tt = 0; tt < 4; ++tt) {
          float p0 = fexp2(sc[qf][tt][0] - M2);
          float p1 = fexp2(sc[qf][tt][1] - M2);
          float p2 = fexp2(sc[qf][tt][2] - M2);
          float p3 = fexp2(sc[qf][tt][3] - M2);
          ss += (p0 + p1) + (p2 + p3);
          pk[tt][0] = cvtpk(p0, p1);
          pk[tt][1] = cvtpk(p2, p3);
        }
        Ll[qf] += ss;
        __builtin_amdgcn_s_setprio(1);
#pragma unroll
        for (int kcb = 0; kcb < 2; ++kcb) {
          const int lo = kcb * 2, hi = kcb * 2 + 1;
          const uint32_t a0 = __shfl(pk[lo][0], s0lane), b0 = __shfl(pk[hi][0], s0lane);
          const uint32_t a1 = __shfl(pk[lo][1], s0lane), b1 = __shfl(pk[hi][1], s0lane);
          const uint32_t a2 = __shfl(pk[lo][0], s1lane), b2 = __shfl(pk[hi][0], s1lane);
          const uint32_t a3 = __shfl(pk[lo][1], s1lane), b3 = __shfl(pk[hi][1], s1lane);
          uint4 uu;
          uu.x = ghi ? b0 : a0; uu.y = ghi ? b1 : a1;
          uu.z = ghi ? b2 : a2; uu.w = ghi ? b3 : a3;
          const bfrag pfrag = __builtin_bit_cast(bfrag, uu);
#pragma unroll
          for (int et = 0; et < 4; ++et)
            accT[qf][et] = __builtin_amdgcn_mfma_f32_16x16x32_bf16(vb[kcb][et], pfrag, accT[qf][et], 0, 0, 0);
        }
        __builtin_amdgcn_s_setprio(0);
      }
    }
    __syncthreads();
  }

#pragma unroll
  for (int qf = 0; qf < 2; ++qf) {
    float Ls = Ll[qf];
    Ls += __shfl_xor(Ls, 16);
    Ls += __shfl_xor(Ls, 32);
    const float inv = 1.f / Ls;
    u16* orow = Og + (size_t)(q0 + qf * 16 + l15) * 1024 + g * 4;
#pragma unroll
    for (int et = 0; et < 4; ++et) {
      uint2 w;
      w.x = cvtpk(accT[qf][et][0] * inv, accT[qf][et][1] * inv);
      w.y = cvtpk(accT[qf][et][2] * inv, accT[qf][et][3] * inv);
      *(uint2*)(orow + et * 16) = w;
    }
  }
}

extern "C" void kernel_launch(void* const* d_in, const int* in_sizes, int n_in,
                              void* d_out, int out_size, void* d_ws, size_t ws_size,
                              hipStream_t stream) {
  const float* keys    = (const float*)d_in[0];
  const float* queries = (const float*)d_in[1];
  const float* values  = (const float*)d_in[2];
  const float* Wq = (const float*)d_in[3];
  const float* bq = (const float*)d_in[4];
  const float* Wk = (const float*)d_in[5];
  const float* bk = (const float*)d_in[6];
  const float* Wv = (const float*)d_in[7];
  const float* bv = (const float*)d_in[8];
  const float* Wo = (const float*)d_in[9];
  const float* bo = (const float*)d_in[10];
  float* out = (float*)d_out;

  char* ws = (char*)d_ws;
  const size_t MB = 1u << 20;
  u16* Wqkvt = (u16*)(ws);               // 0..6 MB
  u16* Wot   = (u16*)(ws + 6 * MB);      // 6..8 MB
  u16* Qb    = (u16*)(ws + 8 * MB);      // 8..24
  u16* Kb    = (u16*)(ws + 24 * MB);     // 24..40
  u16* Vtg   = (u16*)(ws + 40 * MB);     // 40..56
  u16* Ob    = (u16*)(ws + 56 * MB);     // 56..72 (attn output)
  u16* cvQ   = (u16*)(ws + 56 * MB);     // aliases Ob (dead until attn)
  u16* cvK   = (u16*)(ws + 72 * MB);
  u16* cvV   = (u16*)(ws + 88 * MB);

  const dim3 pg(16, 16);
  pack_w_hde<<<pg, 256, 0, stream>>>(Wq, Wqkvt);
  pack_w_hde<<<pg, 256, 0, stream>>>(Wk, Wqkvt + (size_t)1024 * 1024);
  pack_w_hde<<<pg, 256, 0, stream>>>(Wv, Wqkvt + (size_t)2048 * 1024);
  transpose_w<<<pg, 256, 0, stream>>>(Wo, Wot);

  if (ws_size >= 104 * MB) {
    conv_bf16<<<dim3(4096, 3), 256, 0, stream>>>(queries, keys, values, cvQ, cvK, cvV);
    gemm_qkvb<<<dim3(1536), 256, 0, stream>>>(cvQ, cvK, cvV, Wqkvt,
                                              bq, bk, bv, Qb, Kb, Vtg);
  } else {
    gemm_qkv<<<dim3(1536), 256, 0, stream>>>(queries, keys, values, Wqkvt,
                                             bq, bk, bv, Qb, Kb, Vtg);
  }

  attn_fused<<<dim3(512), 512, 0, stream>>>(Qb, Kb, Vtg, Ob);

  gemm_o<<<dim3(512), 256, 0, stream>>>(Ob, Wot, bo, out);
}

// Round 21
// 187.993 us; speedup vs baseline: 1.0545x; 1.0545x over previous
//
#include <hip/hip_runtime.h>
#include <stdint.h>

typedef unsigned short u16;
typedef __attribute__((ext_vector_type(4))) float f32x4;
typedef __attribute__((ext_vector_type(8))) short bfrag;

static __device__ __forceinline__ u16 f2bf(float f) {  // RNE
  union { float f; uint32_t u; } v; v.f = f;
  return (u16)((v.u + 0x7fffu + ((v.u >> 16) & 1u)) >> 16);
}
static __device__ __forceinline__ uint32_t cvtpk(float lo, float hi) {
  uint32_t r;
  asm("v_cvt_pk_bf16_f32 %0, %1, %2" : "=v"(r) : "v"(lo), "v"(hi));
  return r;
}
static __device__ __forceinline__ uint32_t pk2bf(float lo, float hi) {
  union { float f; uint32_t u; } a, b; a.f = lo; b.f = hi;
  return __builtin_amdgcn_perm(b.u + 0x8000u, a.u + 0x8000u, 0x07060302u);
}
// single-instruction 2^x (v_exp_f32 is natively base-2)
static __device__ __forceinline__ float fexp2(float x) {
  float r;
  asm("v_exp_f32 %0, %1" : "=v"(r) : "v"(x));
  return r;
}

#define GLOAD16(gp, lp)                                              \
  __builtin_amdgcn_global_load_lds(                                  \
      (const __attribute__((address_space(1))) uint32_t*)(gp),       \
      (__attribute__((address_space(3))) uint32_t*)(lp), 16, 0, 0)

// ---------------- pack W: [1024][64] f32 slice -> Wt[h*64+e][k] bf16
__global__ __launch_bounds__(256) void pack_w_hde(const float* __restrict__ W,
                                                  u16* __restrict__ Wt) {
  __shared__ float tile[64][65];
  const int h = blockIdx.y, k0 = blockIdx.x * 64;
  const int tid = threadIdx.x;
#pragma unroll
  for (int j = 0; j < 4; ++j) {
    int idx = tid + j * 256;
    int rr = idx >> 4, c4 = (idx & 15) * 4;
    const float4 v = *(const float4*)(W + (size_t)h * 65536 + (size_t)(k0 + rr) * 64 + c4);
    tile[rr][c4 + 0] = v.x; tile[rr][c4 + 1] = v.y;
    tile[rr][c4 + 2] = v.z; tile[rr][c4 + 3] = v.w;
  }
  __syncthreads();
#pragma unroll
  for (int j = 0; j < 4; ++j) {
    int idx = tid + j * 256;
    int ee = idx >> 4, c4 = (idx & 15) * 4;
    uint2 u;
    u.x = f2bf(tile[c4 + 0][ee]) | ((uint32_t)f2bf(tile[c4 + 1][ee]) << 16);
    u.y = f2bf(tile[c4 + 2][ee]) | ((uint32_t)f2bf(tile[c4 + 3][ee]) << 16);
    *(uint2*)(Wt + (size_t)(h * 64 + ee) * 1024 + k0 + c4) = u;
  }
}

// ---------------- transpose Wo: [1024][1024] f32 -> bf16, out[n][k] = Wo[k][n]
__global__ __launch_bounds__(256) void transpose_w(const float* __restrict__ W,
                                                   u16* __restrict__ Wt) {
  __shared__ float tile[64][65];
  const int k0 = blockIdx.x * 64, n0 = blockIdx.y * 64;
  const int tid = threadIdx.x;
#pragma unroll
  for (int j = 0; j < 4; ++j) {
    int idx = tid + j * 256;
    int rr = idx >> 4, c4 = (idx & 15) * 4;
    const float4 v = *(const float4*)(W + (size_t)(k0 + rr) * 1024 + n0 + c4);
    tile[rr][c4 + 0] = v.x; tile[rr][c4 + 1] = v.y;
    tile[rr][c4 + 2] = v.z; tile[rr][c4 + 3] = v.w;
  }
  __syncthreads();
#pragma unroll
  for (int j = 0; j < 4; ++j) {
    int idx = tid + j * 256;
    int ee = idx >> 4, c4 = (idx & 15) * 4;
    uint2 u;
    u.x = f2bf(tile[c4 + 0][ee]) | ((uint32_t)f2bf(tile[c4 + 1][ee]) << 16);
    u.y = f2bf(tile[c4 + 2][ee]) | ((uint32_t)f2bf(tile[c4 + 3][ee]) << 16);
    *(uint2*)(Wt + (size_t)(n0 + ee) * 1024 + k0 + c4) = u;
  }
}

// ---------------- QKV GEMM (R13/R19): f32 A reg-staged, B via global_load_lds,
// XOR chunk swizzle both tiles, 2-phase, 1 barrier/K-step.
// Q chunk pre-scaled by 0.125*log2(e) -> attention scores in log2 domain.
__global__ __launch_bounds__(256) void gemm_qkv(
    const float* __restrict__ Aq, const float* __restrict__ Ak,
    const float* __restrict__ Avv, const u16* __restrict__ Bt,
    const float* __restrict__ bq, const float* __restrict__ bk,
    const float* __restrict__ bv,
    u16* __restrict__ Qb, u16* __restrict__ Kb, u16* __restrict__ Vt) {
  __shared__ u16 As[2][128 * 32];
  __shared__ u16 Bs[2][128 * 32];
  const int tid = threadIdx.x;
  const int n = blockIdx.x;
  const int xcd = n & 7, j = n >> 3;
  const int mb = xcd * 8 + (j & 7);
  const int nb = j >> 3;
  const int chunk = nb >> 3;
  const float* Af = (chunk == 0) ? Aq : (chunk == 1) ? Ak : Avv;
  const int wid = tid >> 6, lane = tid & 63;
  const int wr = wid >> 1, wc = wid & 1;
  const int g = lane >> 4, l15 = lane & 15;
  f32x4 acc[4][4] = {};

  const int bsrc = ((lane & 3) ^ ((lane >> 3) & 3)) * 8;
  const u16* Bg = Bt + (size_t)(nb * 128 + 2 * wid * 16 + (lane >> 2)) * 1024 + bsrc;
  const float* Ap = Af + (size_t)(mb * 128 + (tid >> 2)) * 1024 + (tid & 3) * 8;
  const int arow = tid >> 2;
  const int acs = (((tid & 3) ^ ((tid >> 3) & 3))) * 8;
  const int swzr = (l15 >> 1) & 3;

  float4 fa[2][2];
#pragma unroll
  for (int c = 0; c < 2; ++c) {
    fa[c][0] = *(const float4*)(Ap + (size_t)c * 64 * 1024);
    fa[c][1] = *(const float4*)(Ap + (size_t)c * 64 * 1024 + 4);
  }
#pragma unroll
  for (int c = 0; c < 2; ++c)
    GLOAD16(Bg + (size_t)c * 16 * 1024, &Bs[0][2 * wid * 512 + c * 512]);
#pragma unroll
  for (int c = 0; c < 2; ++c) {
    uint4 u;
    u.x = pk2bf(fa[c][0].x, fa[c][0].y); u.y = pk2bf(fa[c][0].z, fa[c][0].w);
    u.z = pk2bf(fa[c][1].x, fa[c][1].y); u.w = pk2bf(fa[c][1].z, fa[c][1].w);
    *(uint4*)&As[0][(arow + c * 64) * 32 + acs] = u;
  }
  __syncthreads();
  int cur = 0;
  for (int kk = 0; kk < 32; ++kk) {
    if (kk < 31) {
      const int kn = (kk + 1) * 32;
#pragma unroll
      for (int c = 0; c < 2; ++c) {
        fa[c][0] = *(const float4*)(Ap + (size_t)c * 64 * 1024 + kn);
        fa[c][1] = *(const float4*)(Ap + (size_t)c * 64 * 1024 + kn + 4);
      }
#pragma unroll
      for (int c = 0; c < 2; ++c)
        GLOAD16(Bg + (size_t)c * 16 * 1024 + kn, &Bs[cur ^ 1][2 * wid * 512 + c * 512]);
    }
    bfrag a[4], b[4];
#pragma unroll
    for (int m = 0; m < 4; ++m)
      a[m] = __builtin_bit_cast(bfrag,
          *(const uint4*)&As[cur][(wr * 64 + m * 16 + l15) * 32 + ((g ^ swzr)) * 8]);
#pragma unroll
    for (int nn = 0; nn < 4; ++nn)
      b[nn] = __builtin_bit_cast(bfrag,
          *(const uint4*)&Bs[cur][(wc * 64 + nn * 16 + l15) * 32 + ((g ^ swzr)) * 8]);
    __builtin_amdgcn_s_setprio(1);
#pragma unroll
    for (int m = 0; m < 4; ++m)
#pragma unroll
      for (int nn = 0; nn < 4; ++nn)
        acc[m][nn] = __builtin_amdgcn_mfma_f32_16x16x32_bf16(a[m], b[nn], acc[m][nn], 0, 0, 0);
    __builtin_amdgcn_s_setprio(0);
    if (kk < 31) {
#pragma unroll
      for (int c = 0; c < 2; ++c) {
        uint4 u;
        u.x = pk2bf(fa[c][0].x, fa[c][0].y); u.y = pk2bf(fa[c][0].z, fa[c][0].w);
        u.z = pk2bf(fa[c][1].x, fa[c][1].y); u.w = pk2bf(fa[c][1].z, fa[c][1].w);
        *(uint4*)&As[cur ^ 1][(arow + c * 64) * 32 + acs] = u;
      }
      __syncthreads();
      cur ^= 1;
    }
  }

  const int row0 = mb * 128 + wr * 64 + g * 4;
  const int cc0 = (nb & 7) * 128 + wc * 64 + l15;
  const float* bias = (chunk == 0) ? bq : (chunk == 1) ? bk : bv;
  const float qs = (chunk == 0) ? 0.125f * 1.44269504f : 1.0f;  // log2 domain
#pragma unroll
  for (int m = 0; m < 4; ++m) {
#pragma unroll
    for (int nn = 0; nn < 4; ++nn) {
      const int row = row0 + m * 16;
      const int cc = cc0 + nn * 16;
      const float bcv = bias[cc];
      if (chunk < 2) {
        u16* dst = (chunk == 0) ? Qb : Kb;
#pragma unroll
        for (int r = 0; r < 4; ++r)
          dst[(size_t)(row + r) * 1024 + cc] = f2bf((acc[m][nn][r] + bcv) * qs);
      } else {
        u16 w[4];
#pragma unroll
        for (int r = 0; r < 4; ++r) w[r] = f2bf(acc[m][nn][r] + bcv);
        const size_t dst =
            ((size_t)((row >> 11) * 16 + (cc >> 6)) * 64 + (cc & 63)) * 2048 + (row & 2047);
        *(uint2*)(Vt + dst) = *(const uint2*)w;
      }
    }
  }
}

// ---------------- O-projection GEMM (R13, unchanged)
__global__ __launch_bounds__(256) void gemm_o(const u16* __restrict__ Abf,
                                              const u16* __restrict__ Bt,
                                              const float* __restrict__ bo,
                                              float* __restrict__ Of) {
  __shared__ u16 As[2][128 * 32];
  __shared__ u16 Bs[2][128 * 32];
  const int tid = threadIdx.x;
  const int n = blockIdx.x;
  const int xcd = n & 7, j = n >> 3;
  const int mb = xcd * 8 + (j & 7);
  const int nb = j >> 3;
  const int wid = tid >> 6, lane = tid & 63;
  const int wr = wid >> 1, wc = wid & 1;
  const int g = lane >> 4, l15 = lane & 15;
  f32x4 acc[4][4] = {};

  const int bsrc = ((lane & 3) ^ ((lane >> 3) & 3)) * 8;
  const int swzr = (l15 >> 1) & 3;
  const u16* Bg = Bt + (size_t)(nb * 128 + 2 * wid * 16 + (lane >> 2)) * 1024 + bsrc;
  const u16* Ag = Abf + (size_t)(mb * 128 + 2 * wid * 16 + (lane >> 2)) * 1024 + bsrc;

#pragma unroll
  for (int c = 0; c < 2; ++c) {
    GLOAD16(Ag + (size_t)c * 16 * 1024, &As[0][2 * wid * 512 + c * 512]);
    GLOAD16(Bg + (size_t)c * 16 * 1024, &Bs[0][2 * wid * 512 + c * 512]);
  }
  __syncthreads();
  int cur = 0;
  for (int kk = 0; kk < 32; ++kk) {
    if (kk < 31) {
      const int kn = (kk + 1) * 32;
#pragma unroll
      for (int c = 0; c < 2; ++c) {
        GLOAD16(Ag + (size_t)c * 16 * 1024 + kn, &As[cur ^ 1][2 * wid * 512 + c * 512]);
        GLOAD16(Bg + (size_t)c * 16 * 1024 + kn, &Bs[cur ^ 1][2 * wid * 512 + c * 512]);
      }
    }
    bfrag a[4], b[4];
#pragma unroll
    for (int m = 0; m < 4; ++m)
      a[m] = __builtin_bit_cast(bfrag,
          *(const uint4*)&As[cur][(wr * 64 + m * 16 + l15) * 32 + ((g ^ swzr)) * 8]);
#pragma unroll
    for (int nn = 0; nn < 4; ++nn)
      b[nn] = __builtin_bit_cast(bfrag,
          *(const uint4*)&Bs[cur][(wc * 64 + nn * 16 + l15) * 32 + ((g ^ swzr)) * 8]);
    __builtin_amdgcn_s_setprio(1);
#pragma unroll
    for (int m = 0; m < 4; ++m)
#pragma unroll
      for (int nn = 0; nn < 4; ++nn)
        acc[m][nn] = __builtin_amdgcn_mfma_f32_16x16x32_bf16(a[m], b[nn], acc[m][nn], 0, 0, 0);
    __builtin_amdgcn_s_setprio(0);
    if (kk < 31) { __syncthreads(); cur ^= 1; }
  }

  const int row0 = mb * 128 + wr * 64 + g * 4;
  const int col0 = nb * 128 + wc * 64 + l15;
#pragma unroll
  for (int m = 0; m < 4; ++m)
#pragma unroll
    for (int nn = 0; nn < 4; ++nn) {
      const int row = row0 + m * 16, col = col0 + nn * 16;
      const float bcv = bo[col];
#pragma unroll
      for (int r = 0; r < 4; ++r)
        Of[(size_t)(row + r) * 1024 + col] = acc[m][nn][r] + bcv;
    }
}

// ---------------- fused causal flash attention — fixed-max softmax with
// single-instruction v_exp_f32 (base-2). Scores arrive in log2 domain. (R19)
__global__ __launch_bounds__(512) void attn_fused(const u16* __restrict__ Qb,
                                                  const u16* __restrict__ Kb,
                                                  const u16* __restrict__ Vtg,
                                                  u16* __restrict__ Ob) {
  __shared__ u16 KV[2][2][4096];
  const int tid = threadIdx.x;
  const int wid = tid >> 6, lane = tid & 63;
  const int g = lane >> 4, l15 = lane & 15;
  const int n = blockIdx.x;
  const int half = n >> 8, idx = n & 255;
  const int xcd = idx & 7;
  const int bh = xcd * 8 + ((idx >> 3) & 7);
  const int grp = idx >> 6;
  const int u = half ? grp : (7 - grp);
  const int t = u * 8 + wid;
  const int b = bh >> 4, h = bh & 15;
  const size_t baserow = (size_t)b * 2048;
  const u16* Qg = Qb + baserow * 1024 + h * 64;
  const u16* Kg = Kb + baserow * 1024 + h * 64;
  const u16* Vg = Vtg + (size_t)bh * 64 * 2048;
  u16* Og = Ob + baserow * 1024 + h * 64;

  const int q0 = t * 32;
  const int qrow = q0 + l15;
  const int mysteps = (q0 >> 6) + 1;
  const int smax = 4 * u + 4;
  const float M2 = 6.0f;

  const int sr = tid >> 3;
  const int scc = (tid & 7) ^ (sr & 7);
  const u16* Kst = Kg + (size_t)sr * 1024 + scc * 8;
  const u16* Vst = Vg + (size_t)sr * 2048 + scc * 8;

  bfrag qa[2][2];
#pragma unroll
  for (int qf = 0; qf < 2; ++qf)
#pragma unroll
    for (int kh = 0; kh < 2; ++kh)
      qa[qf][kh] = __builtin_bit_cast(bfrag,
          *(const uint4*)(Qg + (size_t)(q0 + qf * 16 + l15) * 1024 + kh * 32 + g * 8));

  f32x4 accT[2][4] = {};
  float Ll[2] = {0.f, 0.f};

  const int s0lane = ((g & 1) << 5) | l15;
  const int s1lane = s0lane + 16;
  const bool ghi = (g >= 2);
  const int swz = l15 & 7;

  GLOAD16(Kst, &KV[0][0][wid * 512]);
  GLOAD16(Vst, &KV[0][1][wid * 512]);
  __syncthreads();

  for (int s = 0; s < smax; ++s) {
    const int cb = s & 1;
    if (s + 1 < smax) {
      const size_t kn = (size_t)(s + 1) << 6;
      GLOAD16(Kst + kn * 1024, &KV[cb ^ 1][0][wid * 512]);
      GLOAD16(Vst + kn, &KV[cb ^ 1][1][wid * 512]);
    }
    if (s < mysteps) {
      const int kv0 = s << 6;
      const bool diag = (s == mysteps - 1);
      const u16* KB = &KV[cb][0][0];
      const u16* VB = &KV[cb][1][0];

      bfrag kb[2][4];
#pragma unroll
      for (int tt = 0; tt < 4; ++tt)
#pragma unroll
        for (int kh = 0; kh < 2; ++kh)
          kb[kh][tt] = __builtin_bit_cast(bfrag,
              *(const uint4*)&KB[(tt * 16 + l15) * 64 + (((kh << 2) | g) ^ swz) * 8]);

      f32x4 sc[2][4];
      __builtin_amdgcn_s_setprio(1);
#pragma unroll
      for (int qf = 0; qf < 2; ++qf)
#pragma unroll
        for (int tt = 0; tt < 4; ++tt) {
          f32x4 z = {0.f, 0.f, 0.f, 0.f};
          z = __builtin_amdgcn_mfma_f32_16x16x32_bf16(kb[0][tt], qa[qf][0], z, 0, 0, 0);
          z = __builtin_amdgcn_mfma_f32_16x16x32_bf16(kb[1][tt], qa[qf][1], z, 0, 0, 0);
          sc[qf][tt] = z;
        }
      __builtin_amdgcn_s_setprio(0);

      bfrag vb[2][4];
#pragma unroll
      for (int et = 0; et < 4; ++et)
#pragma unroll
        for (int kcb = 0; kcb < 2; ++kcb)
          vb[kcb][et] = __builtin_bit_cast(bfrag,
              *(const uint4*)&VB[(et * 16 + l15) * 64 + (((kcb << 2) | g) ^ swz) * 8]);

#pragma unroll
      for (int qf = 0; qf < 2; ++qf) {
        if (diag) {
          const int qq = qrow + qf * 16;
#pragma unroll
          for (int tt = 0; tt < 4; ++tt) {
            const int kvb = kv0 + tt * 16 + g * 4;
#pragma unroll
            for (int r = 0; r < 4; ++r)
              sc[qf][tt][r] = (kvb + r <= qq) ? sc[qf][tt][r] : -100.0f;
          }
        }
        uint32_t pk[4][2];
        float ss = 0.f;
#pragma unroll
        for (int tt = 0; tt < 4; ++tt) {
          float p0 = fexp2(sc[qf][tt][0] - M2);
          float p1 = fexp2(sc[qf][tt][1] - M2);
          float p2 = fexp2(sc[qf][tt][2] - M2);
          float p3 = fexp2(sc[qf][tt][3] - M2);
          ss += (p0 + p1) + (p2 + p3);
          pk[tt][0] = cvtpk(p0, p1);
          pk[tt][1] = cvtpk(p2, p3);
        }
        Ll[qf] += ss;
        __builtin_amdgcn_s_setprio(1);
#pragma unroll
        for (int kcb = 0; kcb < 2; ++kcb) {
          const int lo = kcb * 2, hi = kcb * 2 + 1;
          const uint32_t a0 = __shfl(pk[lo][0], s0lane), b0 = __shfl(pk[hi][0], s0lane);
          const uint32_t a1 = __shfl(pk[lo][1], s0lane), b1 = __shfl(pk[hi][1], s0lane);
          const uint32_t a2 = __shfl(pk[lo][0], s1lane), b2 = __shfl(pk[hi][0], s1lane);
          const uint32_t a3 = __shfl(pk[lo][1], s1lane), b3 = __shfl(pk[hi][1], s1lane);
          uint4 uu;
          uu.x = ghi ? b0 : a0; uu.y = ghi ? b1 : a1;
          uu.z = ghi ? b2 : a2; uu.w = ghi ? b3 : a3;
          const bfrag pfrag = __builtin_bit_cast(bfrag, uu);
#pragma unroll
          for (int et = 0; et < 4; ++et)
            accT[qf][et] = __builtin_amdgcn_mfma_f32_16x16x32_bf16(vb[kcb][et], pfrag, accT[qf][et], 0, 0, 0);
        }
        __builtin_amdgcn_s_setprio(0);
      }
    }
    __syncthreads();
  }

#pragma unroll
  for (int qf = 0; qf < 2; ++qf) {
    float Ls = Ll[qf];
    Ls += __shfl_xor(Ls, 16);
    Ls += __shfl_xor(Ls, 32);
    const float inv = 1.f / Ls;
    u16* orow = Og + (size_t)(q0 + qf * 16 + l15) * 1024 + g * 4;
#pragma unroll
    for (int et = 0; et < 4; ++et) {
      uint2 w;
      w.x = cvtpk(accT[qf][et][0] * inv, accT[qf][et][1] * inv);
      w.y = cvtpk(accT[qf][et][2] * inv, accT[qf][et][3] * inv);
      *(uint2*)(orow + et * 16) = w;
    }
  }
}

extern "C" void kernel_launch(void* const* d_in, const int* in_sizes, int n_in,
                              void* d_out, int out_size, void* d_ws, size_t ws_size,
                              hipStream_t stream) {
  const float* keys    = (const float*)d_in[0];
  const float* queries = (const float*)d_in[1];
  const float* values  = (const float*)d_in[2];
  const float* Wq = (const float*)d_in[3];
  const float* bq = (const float*)d_in[4];
  const float* Wk = (const float*)d_in[5];
  const float* bk = (const float*)d_in[6];
  const float* Wv = (const float*)d_in[7];
  const float* bv = (const float*)d_in[8];
  const float* Wo = (const float*)d_in[9];
  const float* bo = (const float*)d_in[10];
  float* out = (float*)d_out;

  char* ws = (char*)d_ws;
  const size_t MB = 1u << 20;
  u16* Wqkvt = (u16*)(ws);               // 0..6 MB
  u16* Wot   = (u16*)(ws + 6 * MB);      // 6..8 MB
  u16* Qb    = (u16*)(ws + 8 * MB);      // 8..24
  u16* Kb    = (u16*)(ws + 24 * MB);     // 24..40
  u16* Vtg   = (u16*)(ws + 40 * MB);     // 40..56
  u16* Ob    = (u16*)(ws + 56 * MB);     // 56..72

  const dim3 pg(16, 16);
  pack_w_hde<<<pg, 256, 0, stream>>>(Wq, Wqkvt);
  pack_w_hde<<<pg, 256, 0, stream>>>(Wk, Wqkvt + (size_t)1024 * 1024);
  pack_w_hde<<<pg, 256, 0, stream>>>(Wv, Wqkvt + (size_t)2048 * 1024);
  transpose_w<<<pg, 256, 0, stream>>>(Wo, Wot);

  gemm_qkv<<<dim3(1536), 256, 0, stream>>>(queries, keys, values, Wqkvt,
                                           bq, bk, bv, Qb, Kb, Vtg);

  attn_fused<<<dim3(512), 512, 0, stream>>>(Qb, Kb, Vtg, Ob);

  gemm_o<<<dim3(512), 256, 0, stream>>>(Ob, Wot, bo, out);
}

// Round 22
// 185.283 us; speedup vs baseline: 1.0699x; 1.0146x over previous
//
#include <hip/hip_runtime.h>
#include <stdint.h>

typedef unsigned short u16;
typedef __attribute__((ext_vector_type(4))) float f32x4;
typedef __attribute__((ext_vector_type(8))) short bfrag;

static __device__ __forceinline__ u16 f2bf(float f) {  // RNE
  union { float f; uint32_t u; } v; v.f = f;
  return (u16)((v.u + 0x7fffu + ((v.u >> 16) & 1u)) >> 16);
}
static __device__ __forceinline__ uint32_t cvtpk(float lo, float hi) {
  uint32_t r;
  asm("v_cvt_pk_bf16_f32 %0, %1, %2" : "=v"(r) : "v"(lo), "v"(hi));
  return r;
}
static __device__ __forceinline__ uint32_t pk2bf(float lo, float hi) {
  union { float f; uint32_t u; } a, b; a.f = lo; b.f = hi;
  return __builtin_amdgcn_perm(b.u + 0x8000u, a.u + 0x8000u, 0x07060302u);
}
// single-instruction 2^x (v_exp_f32 is natively base-2)
static __device__ __forceinline__ float fexp2(float x) {
  float r;
  asm("v_exp_f32 %0, %1" : "=v"(r) : "v"(x));
  return r;
}

#define GLOAD16(gp, lp)                                              \
  __builtin_amdgcn_global_load_lds(                                  \
      (const __attribute__((address_space(1))) uint32_t*)(gp),       \
      (__attribute__((address_space(3))) uint32_t*)(lp), 16, 0, 0)

// ---------------- pack W: [1024][64] f32 slice -> Wt[h*64+e][k] bf16
__global__ __launch_bounds__(256) void pack_w_hde(const float* __restrict__ W,
                                                  u16* __restrict__ Wt) {
  __shared__ float tile[64][65];
  const int h = blockIdx.y, k0 = blockIdx.x * 64;
  const int tid = threadIdx.x;
#pragma unroll
  for (int j = 0; j < 4; ++j) {
    int idx = tid + j * 256;
    int rr = idx >> 4, c4 = (idx & 15) * 4;
    const float4 v = *(const float4*)(W + (size_t)h * 65536 + (size_t)(k0 + rr) * 64 + c4);
    tile[rr][c4 + 0] = v.x; tile[rr][c4 + 1] = v.y;
    tile[rr][c4 + 2] = v.z; tile[rr][c4 + 3] = v.w;
  }
  __syncthreads();
#pragma unroll
  for (int j = 0; j < 4; ++j) {
    int idx = tid + j * 256;
    int ee = idx >> 4, c4 = (idx & 15) * 4;
    uint2 u;
    u.x = f2bf(tile[c4 + 0][ee]) | ((uint32_t)f2bf(tile[c4 + 1][ee]) << 16);
    u.y = f2bf(tile[c4 + 2][ee]) | ((uint32_t)f2bf(tile[c4 + 3][ee]) << 16);
    *(uint2*)(Wt + (size_t)(h * 64 + ee) * 1024 + k0 + c4) = u;
  }
}

// ---------------- transpose Wo: [1024][1024] f32 -> bf16, out[n][k] = Wo[k][n]
__global__ __launch_bounds__(256) void transpose_w(const float* __restrict__ W,
                                                   u16* __restrict__ Wt) {
  __shared__ float tile[64][65];
  const int k0 = blockIdx.x * 64, n0 = blockIdx.y * 64;
  const int tid = threadIdx.x;
#pragma unroll
  for (int j = 0; j < 4; ++j) {
    int idx = tid + j * 256;
    int rr = idx >> 4, c4 = (idx & 15) * 4;
    const float4 v = *(const float4*)(W + (size_t)(k0 + rr) * 1024 + n0 + c4);
    tile[rr][c4 + 0] = v.x; tile[rr][c4 + 1] = v.y;
    tile[rr][c4 + 2] = v.z; tile[rr][c4 + 3] = v.w;
  }
  __syncthreads();
#pragma unroll
  for (int j = 0; j < 4; ++j) {
    int idx = tid + j * 256;
    int ee = idx >> 4, c4 = (idx & 15) * 4;
    uint2 u;
    u.x = f2bf(tile[c4 + 0][ee]) | ((uint32_t)f2bf(tile[c4 + 1][ee]) << 16);
    u.y = f2bf(tile[c4 + 2][ee]) | ((uint32_t)f2bf(tile[c4 + 3][ee]) << 16);
    *(uint2*)(Wt + (size_t)(n0 + ee) * 1024 + k0 + c4) = u;
  }
}

// ---------------- QKV GEMM, 512-thr blocks: 128 rows x 256 cols per block.
// 8 waves (2M x 4N); A f32 staged ONCE per block (per-thread convert cost
// halved vs 256-thr version); B (256 cols) via global_load_lds dbuf.
// LDS 48KB -> 3 blocks/CU x 8 waves = 24 waves/CU (TLP preserved; R17's
// failure was 12). Grid 768 = exactly 3/CU, zero tail. Same swizzles,
// 2-phase, 1 barrier/K-step. Q chunk pre-scaled by 0.125*log2(e).
__global__ __launch_bounds__(512) void gemm_qkv(
    const float* __restrict__ Aq, const float* __restrict__ Ak,
    const float* __restrict__ Avv, const u16* __restrict__ Bt,
    const float* __restrict__ bq, const float* __restrict__ bk,
    const float* __restrict__ bv,
    u16* __restrict__ Qb, u16* __restrict__ Kb, u16* __restrict__ Vt) {
  __shared__ u16 As[2][128 * 32];   // 16 KB
  __shared__ u16 Bs[2][256 * 32];   // 32 KB
  const int tid = threadIdx.x;
  const int n = blockIdx.x;            // 0..767
  const int xcd = n & 7, j = n >> 3;   // j 0..95
  const int mb = xcd * 8 + (j & 7);    // 0..63
  const int nb2 = j >> 3;              // 0..11 (256-col tiles)
  const int chunk = nb2 >> 2;          // 0:Q 1:K 2:V
  const float* Af = (chunk == 0) ? Aq : (chunk == 1) ? Ak : Avv;
  const int wid = tid >> 6, lane = tid & 63;
  const int wr = wid >> 2, wc = wid & 3;   // 2 M-waves x 4 N-waves
  const int g = lane >> 4, l15 = lane & 15;
  f32x4 acc[4][4] = {};

  const int bsrc = ((lane & 3) ^ ((lane >> 3) & 3)) * 8;
  const u16* Bg = Bt + (size_t)(nb2 * 256 + 2 * wid * 16 + (lane >> 2)) * 1024 + bsrc;
  const float* Ap = Af + (size_t)(mb * 128 + (tid >> 2)) * 1024 + (tid & 3) * 8;
  const int arow = tid >> 2;                        // 0..127
  const int acs = (((tid & 3) ^ ((tid >> 3) & 3))) * 8;
  const int swzr = (l15 >> 1) & 3;

  float4 fa0 = *(const float4*)(Ap);
  float4 fa1 = *(const float4*)(Ap + 4);
#pragma unroll
  for (int c = 0; c < 2; ++c)
    GLOAD16(Bg + (size_t)c * 16 * 1024, &Bs[0][(2 * wid + c) * 512]);
  {
    uint4 u;
    u.x = pk2bf(fa0.x, fa0.y); u.y = pk2bf(fa0.z, fa0.w);
    u.z = pk2bf(fa1.x, fa1.y); u.w = pk2bf(fa1.z, fa1.w);
    *(uint4*)&As[0][arow * 32 + acs] = u;
  }
  __syncthreads();
  int cur = 0;
  for (int kk = 0; kk < 32; ++kk) {
    if (kk < 31) {
      const int kn = (kk + 1) * 32;
      fa0 = *(const float4*)(Ap + kn);
      fa1 = *(const float4*)(Ap + kn + 4);
#pragma unroll
      for (int c = 0; c < 2; ++c)
        GLOAD16(Bg + (size_t)c * 16 * 1024 + kn, &Bs[cur ^ 1][(2 * wid + c) * 512]);
    }
    bfrag a[4], b[4];
#pragma unroll
    for (int m = 0; m < 4; ++m)
      a[m] = __builtin_bit_cast(bfrag,
          *(const uint4*)&As[cur][(wr * 64 + m * 16 + l15) * 32 + ((g ^ swzr)) * 8]);
#pragma unroll
    for (int nn = 0; nn < 4; ++nn)
      b[nn] = __builtin_bit_cast(bfrag,
          *(const uint4*)&Bs[cur][(wc * 64 + nn * 16 + l15) * 32 + ((g ^ swzr)) * 8]);
    __builtin_amdgcn_s_setprio(1);
#pragma unroll
    for (int m = 0; m < 4; ++m)
#pragma unroll
      for (int nn = 0; nn < 4; ++nn)
        acc[m][nn] = __builtin_amdgcn_mfma_f32_16x16x32_bf16(a[m], b[nn], acc[m][nn], 0, 0, 0);
    __builtin_amdgcn_s_setprio(0);
    if (kk < 31) {
      uint4 u;
      u.x = pk2bf(fa0.x, fa0.y); u.y = pk2bf(fa0.z, fa0.w);
      u.z = pk2bf(fa1.x, fa1.y); u.w = pk2bf(fa1.z, fa1.w);
      *(uint4*)&As[cur ^ 1][arow * 32 + acs] = u;
      __syncthreads();
      cur ^= 1;
    }
  }

  const int row0 = mb * 128 + wr * 64 + g * 4;
  const int ccL = (nb2 & 3) * 256 + wc * 64 + l15;  // col within chunk, 0..1023
  const float* bias = (chunk == 0) ? bq : (chunk == 1) ? bk : bv;
  const float qs = (chunk == 0) ? 0.125f * 1.44269504f : 1.0f;  // log2 domain
#pragma unroll
  for (int m = 0; m < 4; ++m) {
#pragma unroll
    for (int nn = 0; nn < 4; ++nn) {
      const int row = row0 + m * 16;
      const int cc = ccL + nn * 16;
      const float bcv = bias[cc];
      if (chunk < 2) {
        u16* dst = (chunk == 0) ? Qb : Kb;
#pragma unroll
        for (int r = 0; r < 4; ++r)
          dst[(size_t)(row + r) * 1024 + cc] = f2bf((acc[m][nn][r] + bcv) * qs);
      } else {
        u16 w[4];
#pragma unroll
        for (int r = 0; r < 4; ++r) w[r] = f2bf(acc[m][nn][r] + bcv);
        const size_t dst =
            ((size_t)((row >> 11) * 16 + (cc >> 6)) * 64 + (cc & 63)) * 2048 + (row & 2047);
        *(uint2*)(Vt + dst) = *(const uint2*)w;
      }
    }
  }
}

// ---------------- O-projection GEMM (R13, unchanged)
__global__ __launch_bounds__(256) void gemm_o(const u16* __restrict__ Abf,
                                              const u16* __restrict__ Bt,
                                              const float* __restrict__ bo,
                                              float* __restrict__ Of) {
  __shared__ u16 As[2][128 * 32];
  __shared__ u16 Bs[2][128 * 32];
  const int tid = threadIdx.x;
  const int n = blockIdx.x;
  const int xcd = n & 7, j = n >> 3;
  const int mb = xcd * 8 + (j & 7);
  const int nb = j >> 3;
  const int wid = tid >> 6, lane = tid & 63;
  const int wr = wid >> 1, wc = wid & 1;
  const int g = lane >> 4, l15 = lane & 15;
  f32x4 acc[4][4] = {};

  const int bsrc = ((lane & 3) ^ ((lane >> 3) & 3)) * 8;
  const int swzr = (l15 >> 1) & 3;
  const u16* Bg = Bt + (size_t)(nb * 128 + 2 * wid * 16 + (lane >> 2)) * 1024 + bsrc;
  const u16* Ag = Abf + (size_t)(mb * 128 + 2 * wid * 16 + (lane >> 2)) * 1024 + bsrc;

#pragma unroll
  for (int c = 0; c < 2; ++c) {
    GLOAD16(Ag + (size_t)c * 16 * 1024, &As[0][2 * wid * 512 + c * 512]);
    GLOAD16(Bg + (size_t)c * 16 * 1024, &Bs[0][2 * wid * 512 + c * 512]);
  }
  __syncthreads();
  int cur = 0;
  for (int kk = 0; kk < 32; ++kk) {
    if (kk < 31) {
      const int kn = (kk + 1) * 32;
#pragma unroll
      for (int c = 0; c < 2; ++c) {
        GLOAD16(Ag + (size_t)c * 16 * 1024 + kn, &As[cur ^ 1][2 * wid * 512 + c * 512]);
        GLOAD16(Bg + (size_t)c * 16 * 1024 + kn, &Bs[cur ^ 1][2 * wid * 512 + c * 512]);
      }
    }
    bfrag a[4], b[4];
#pragma unroll
    for (int m = 0; m < 4; ++m)
      a[m] = __builtin_bit_cast(bfrag,
          *(const uint4*)&As[cur][(wr * 64 + m * 16 + l15) * 32 + ((g ^ swzr)) * 8]);
#pragma unroll
    for (int nn = 0; nn < 4; ++nn)
      b[nn] = __builtin_bit_cast(bfrag,
          *(const uint4*)&Bs[cur][(wc * 64 + nn * 16 + l15) * 32 + ((g ^ swzr)) * 8]);
    __builtin_amdgcn_s_setprio(1);
#pragma unroll
    for (int m = 0; m < 4; ++m)
#pragma unroll
      for (int nn = 0; nn < 4; ++nn)
        acc[m][nn] = __builtin_amdgcn_mfma_f32_16x16x32_bf16(a[m], b[nn], acc[m][nn], 0, 0, 0);
    __builtin_amdgcn_s_setprio(0);
    if (kk < 31) { __syncthreads(); cur ^= 1; }
  }

  const int row0 = mb * 128 + wr * 64 + g * 4;
  const int col0 = nb * 128 + wc * 64 + l15;
#pragma unroll
  for (int m = 0; m < 4; ++m)
#pragma unroll
    for (int nn = 0; nn < 4; ++nn) {
      const int row = row0 + m * 16, col = col0 + nn * 16;
      const float bcv = bo[col];
#pragma unroll
      for (int r = 0; r < 4; ++r)
        Of[(size_t)(row + r) * 1024 + col] = acc[m][nn][r] + bcv;
    }
}

// ---------------- fused causal flash attention — fixed-max softmax with
// single-instruction v_exp_f32 (base-2). Scores arrive in log2 domain. (R19)
__global__ __launch_bounds__(512) void attn_fused(const u16* __restrict__ Qb,
                                                  const u16* __restrict__ Kb,
                                                  const u16* __restrict__ Vtg,
                                                  u16* __restrict__ Ob) {
  __shared__ u16 KV[2][2][4096];
  const int tid = threadIdx.x;
  const int wid = tid >> 6, lane = tid & 63;
  const int g = lane >> 4, l15 = lane & 15;
  const int n = blockIdx.x;
  const int half = n >> 8, idx = n & 255;
  const int xcd = idx & 7;
  const int bh = xcd * 8 + ((idx >> 3) & 7);
  const int grp = idx >> 6;
  const int u = half ? grp : (7 - grp);
  const int t = u * 8 + wid;
  const int b = bh >> 4, h = bh & 15;
  const size_t baserow = (size_t)b * 2048;
  const u16* Qg = Qb + baserow * 1024 + h * 64;
  const u16* Kg = Kb + baserow * 1024 + h * 64;
  const u16* Vg = Vtg + (size_t)bh * 64 * 2048;
  u16* Og = Ob + baserow * 1024 + h * 64;

  const int q0 = t * 32;
  const int qrow = q0 + l15;
  const int mysteps = (q0 >> 6) + 1;
  const int smax = 4 * u + 4;
  const float M2 = 6.0f;

  const int sr = tid >> 3;
  const int scc = (tid & 7) ^ (sr & 7);
  const u16* Kst = Kg + (size_t)sr * 1024 + scc * 8;
  const u16* Vst = Vg + (size_t)sr * 2048 + scc * 8;

  bfrag qa[2][2];
#pragma unroll
  for (int qf = 0; qf < 2; ++qf)
#pragma unroll
    for (int kh = 0; kh < 2; ++kh)
      qa[qf][kh] = __builtin_bit_cast(bfrag,
          *(const uint4*)(Qg + (size_t)(q0 + qf * 16 + l15) * 1024 + kh * 32 + g * 8));

  f32x4 accT[2][4] = {};
  float Ll[2] = {0.f, 0.f};

  const int s0lane = ((g & 1) << 5) | l15;
  const int s1lane = s0lane + 16;
  const bool ghi = (g >= 2);
  const int swz = l15 & 7;

  GLOAD16(Kst, &KV[0][0][wid * 512]);
  GLOAD16(Vst, &KV[0][1][wid * 512]);
  __syncthreads();

  for (int s = 0; s < smax; ++s) {
    const int cb = s & 1;
    if (s + 1 < smax) {
      const size_t kn = (size_t)(s + 1) << 6;
      GLOAD16(Kst + kn * 1024, &KV[cb ^ 1][0][wid * 512]);
      GLOAD16(Vst + kn, &KV[cb ^ 1][1][wid * 512]);
    }
    if (s < mysteps) {
      const int kv0 = s << 6;
      const bool diag = (s == mysteps - 1);
      const u16* KB = &KV[cb][0][0];
      const u16* VB = &KV[cb][1][0];

      bfrag kb[2][4];
#pragma unroll
      for (int tt = 0; tt < 4; ++tt)
#pragma unroll
        for (int kh = 0; kh < 2; ++kh)
          kb[kh][tt] = __builtin_bit_cast(bfrag,
              *(const uint4*)&KB[(tt * 16 + l15) * 64 + (((kh << 2) | g) ^ swz) * 8]);

      f32x4 sc[2][4];
      __builtin_amdgcn_s_setprio(1);
#pragma unroll
      for (int qf = 0; qf < 2; ++qf)
#pragma unroll
        for (int tt = 0; tt < 4; ++tt) {
          f32x4 z = {0.f, 0.f, 0.f, 0.f};
          z = __builtin_amdgcn_mfma_f32_16x16x32_bf16(kb[0][tt], qa[qf][0], z, 0, 0, 0);
          z = __builtin_amdgcn_mfma_f32_16x16x32_bf16(kb[1][tt], qa[qf][1], z, 0, 0, 0);
          sc[qf][tt] = z;
        }
      __builtin_amdgcn_s_setprio(0);

      bfrag vb[2][4];
#pragma unroll
      for (int et = 0; et < 4; ++et)
#pragma unroll
        for (int kcb = 0; kcb < 2; ++kcb)
          vb[kcb][et] = __builtin_bit_cast(bfrag,
              *(const uint4*)&VB[(et * 16 + l15) * 64 + (((kcb << 2) | g) ^ swz) * 8]);

#pragma unroll
      for (int qf = 0; qf < 2; ++qf) {
        if (diag) {
          const int qq = qrow + qf * 16;
#pragma unroll
          for (int tt = 0; tt < 4; ++tt) {
            const int kvb = kv0 + tt * 16 + g * 4;
#pragma unroll
            for (int r = 0; r < 4; ++r)
              sc[qf][tt][r] = (kvb + r <= qq) ? sc[qf][tt][r] : -100.0f;
          }
        }
        uint32_t pk[4][2];
        float ss = 0.f;
#pragma unroll
        for (int tt = 0; tt < 4; ++tt) {
          float p0 = fexp2(sc[qf][tt][0] - M2);
          float p1 = fexp2(sc[qf][tt][1] - M2);
          float p2 = fexp2(sc[qf][tt][2] - M2);
          float p3 = fexp2(sc[qf][tt][3] - M2);
          ss += (p0 + p1) + (p2 + p3);
          pk[tt][0] = cvtpk(p0, p1);
          pk[tt][1] = cvtpk(p2, p3);
        }
        Ll[qf] += ss;
        __builtin_amdgcn_s_setprio(1);
#pragma unroll
        for (int kcb = 0; kcb < 2; ++kcb) {
          const int lo = kcb * 2, hi = kcb * 2 + 1;
          const uint32_t a0 = __shfl(pk[lo][0], s0lane), b0 = __shfl(pk[hi][0], s0lane);
          const uint32_t a1 = __shfl(pk[lo][1], s0lane), b1 = __shfl(pk[hi][1], s0lane);
          const uint32_t a2 = __shfl(pk[lo][0], s1lane), b2 = __shfl(pk[hi][0], s1lane);
          const uint32_t a3 = __shfl(pk[lo][1], s1lane), b3 = __shfl(pk[hi][1], s1lane);
          uint4 uu;
          uu.x = ghi ? b0 : a0; uu.y = ghi ? b1 : a1;
          uu.z = ghi ? b2 : a2; uu.w = ghi ? b3 : a3;
          const bfrag pfrag = __builtin_bit_cast(bfrag, uu);
#pragma unroll
          for (int et = 0; et < 4; ++et)
            accT[qf][et] = __builtin_amdgcn_mfma_f32_16x16x32_bf16(vb[kcb][et], pfrag, accT[qf][et], 0, 0, 0);
        }
        __builtin_amdgcn_s_setprio(0);
      }
    }
    __syncthreads();
  }

#pragma unroll
  for (int qf = 0; qf < 2; ++qf) {
    float Ls = Ll[qf];
    Ls += __shfl_xor(Ls, 16);
    Ls += __shfl_xor(Ls, 32);
    const float inv = 1.f / Ls;
    u16* orow = Og + (size_t)(q0 + qf * 16 + l15) * 1024 + g * 4;
#pragma unroll
    for (int et = 0; et < 4; ++et) {
      uint2 w;
      w.x = cvtpk(accT[qf][et][0] * inv, accT[qf][et][1] * inv);
      w.y = cvtpk(accT[qf][et][2] * inv, accT[qf][et][3] * inv);
      *(uint2*)(orow + et * 16) = w;
    }
  }
}

extern "C" void kernel_launch(void* const* d_in, const int* in_sizes, int n_in,
                              void* d_out, int out_size, void* d_ws, size_t ws_size,
                              hipStream_t stream) {
  const float* keys    = (const float*)d_in[0];
  const float* queries = (const float*)d_in[1];
  const float* values  = (const float*)d_in[2];
  const float* Wq = (const float*)d_in[3];
  const float* bq = (const float*)d_in[4];
  const float* Wk = (const float*)d_in[5];
  const float* bk = (const float*)d_in[6];
  const float* Wv = (const float*)d_in[7];
  const float* bv = (const float*)d_in[8];
  const float* Wo = (const float*)d_in[9];
  const float* bo = (const float*)d_in[10];
  float* out = (float*)d_out;

  char* ws = (char*)d_ws;
  const size_t MB = 1u << 20;
  u16* Wqkvt = (u16*)(ws);               // 0..6 MB
  u16* Wot   = (u16*)(ws + 6 * MB);      // 6..8 MB
  u16* Qb    = (u16*)(ws + 8 * MB);      // 8..24
  u16* Kb    = (u16*)(ws + 24 * MB);     // 24..40
  u16* Vtg   = (u16*)(ws + 40 * MB);     // 40..56
  u16* Ob    = (u16*)(ws + 56 * MB);     // 56..72

  const dim3 pg(16, 16);
  pack_w_hde<<<pg, 256, 0, stream>>>(Wq, Wqkvt);
  pack_w_hde<<<pg, 256, 0, stream>>>(Wk, Wqkvt + (size_t)1024 * 1024);
  pack_w_hde<<<pg, 256, 0, stream>>>(Wv, Wqkvt + (size_t)2048 * 1024);
  transpose_w<<<pg, 256, 0, stream>>>(Wo, Wot);

  gemm_qkv<<<dim3(768), 512, 0, stream>>>(queries, keys, values, Wqkvt,
                                          bq, bk, bv, Qb, Kb, Vtg);

  attn_fused<<<dim3(512), 512, 0, stream>>>(Qb, Kb, Vtg, Ob);

  gemm_o<<<dim3(512), 256, 0, stream>>>(Ob, Wot, bo, out);
}

// Round 23
// 183.634 us; speedup vs baseline: 1.0795x; 1.0090x over previous
//
#include <hip/hip_runtime.h>
#include <stdint.h>

typedef unsigned short u16;
typedef __attribute__((ext_vector_type(4))) float f32x4;
typedef __attribute__((ext_vector_type(8))) short bfrag;

static __device__ __forceinline__ u16 f2bf(float f) {  // RNE
  union { float f; uint32_t u; } v; v.f = f;
  return (u16)((v.u + 0x7fffu + ((v.u >> 16) & 1u)) >> 16);
}
static __device__ __forceinline__ uint32_t cvtpk(float lo, float hi) {
  uint32_t r;
  asm("v_cvt_pk_bf16_f32 %0, %1, %2" : "=v"(r) : "v"(lo), "v"(hi));
  return r;
}
static __device__ __forceinline__ uint32_t pk2bf(float lo, float hi) {
  union { float f; uint32_t u; } a, b; a.f = lo; b.f = hi;
  return __builtin_amdgcn_perm(b.u + 0x8000u, a.u + 0x8000u, 0x07060302u);
}
// single-instruction 2^x (v_exp_f32 is natively base-2)
static __device__ __forceinline__ float fexp2(float x) {
  float r;
  asm("v_exp_f32 %0, %1" : "=v"(r) : "v"(x));
  return r;
}

#define GLOAD16(gp, lp)                                              \
  __builtin_amdgcn_global_load_lds(                                  \
      (const __attribute__((address_space(1))) uint32_t*)(gp),       \
      (__attribute__((address_space(3))) uint32_t*)(lp), 16, 0, 0)

// ---------------- pack W: [1024][64] f32 slice -> Wt[h*64+e][k] bf16
__global__ __launch_bounds__(256) void pack_w_hde(const float* __restrict__ W,
                                                  u16* __restrict__ Wt) {
  __shared__ float tile[64][65];
  const int h = blockIdx.y, k0 = blockIdx.x * 64;
  const int tid = threadIdx.x;
#pragma unroll
  for (int j = 0; j < 4; ++j) {
    int idx = tid + j * 256;
    int rr = idx >> 4, c4 = (idx & 15) * 4;
    const float4 v = *(const float4*)(W + (size_t)h * 65536 + (size_t)(k0 + rr) * 64 + c4);
    tile[rr][c4 + 0] = v.x; tile[rr][c4 + 1] = v.y;
    tile[rr][c4 + 2] = v.z; tile[rr][c4 + 3] = v.w;
  }
  __syncthreads();
#pragma unroll
  for (int j = 0; j < 4; ++j) {
    int idx = tid + j * 256;
    int ee = idx >> 4, c4 = (idx & 15) * 4;
    uint2 u;
    u.x = f2bf(tile[c4 + 0][ee]) | ((uint32_t)f2bf(tile[c4 + 1][ee]) << 16);
    u.y = f2bf(tile[c4 + 2][ee]) | ((uint32_t)f2bf(tile[c4 + 3][ee]) << 16);
    *(uint2*)(Wt + (size_t)(h * 64 + ee) * 1024 + k0 + c4) = u;
  }
}

// ---------------- transpose Wo: [1024][1024] f32 -> bf16, out[n][k] = Wo[k][n]
__global__ __launch_bounds__(256) void transpose_w(const float* __restrict__ W,
                                                   u16* __restrict__ Wt) {
  __shared__ float tile[64][65];
  const int k0 = blockIdx.x * 64, n0 = blockIdx.y * 64;
  const int tid = threadIdx.x;
#pragma unroll
  for (int j = 0; j < 4; ++j) {
    int idx = tid + j * 256;
    int rr = idx >> 4, c4 = (idx & 15) * 4;
    const float4 v = *(const float4*)(W + (size_t)(k0 + rr) * 1024 + n0 + c4);
    tile[rr][c4 + 0] = v.x; tile[rr][c4 + 1] = v.y;
    tile[rr][c4 + 2] = v.z; tile[rr][c4 + 3] = v.w;
  }
  __syncthreads();
#pragma unroll
  for (int j = 0; j < 4; ++j) {
    int idx = tid + j * 256;
    int ee = idx >> 4, c4 = (idx & 15) * 4;
    uint2 u;
    u.x = f2bf(tile[c4 + 0][ee]) | ((uint32_t)f2bf(tile[c4 + 1][ee]) << 16);
    u.y = f2bf(tile[c4 + 2][ee]) | ((uint32_t)f2bf(tile[c4 + 3][ee]) << 16);
    *(uint2*)(Wt + (size_t)(n0 + ee) * 1024 + k0 + c4) = u;
  }
}

// ---------------- QKV GEMM, 512-thr, 128x256 tile, TRIPLE-BUFFERED B with
// raw s_barrier + counted vmcnt: loads for K-step kk+1 issued at step kk-1
// (full-step lead); end-of-step wait = vmcnt(4) -> the 4 newest prefetches
// (A+B for kk+2) stay in flight ACROSS the barrier (never drained; this was
// the ~500cy/step stall under __syncthreads). A f32 reg-double-buffered with
// the convert moved to step START (data loaded one step earlier).
__global__ __launch_bounds__(512) void gemm_qkv(
    const float* __restrict__ Aq, const float* __restrict__ Ak,
    const float* __restrict__ Avv, const u16* __restrict__ Bt,
    const float* __restrict__ bq, const float* __restrict__ bk,
    const float* __restrict__ bv,
    u16* __restrict__ Qb, u16* __restrict__ Kb, u16* __restrict__ Vt) {
  __shared__ u16 As[2][128 * 32];   // 16 KB
  __shared__ u16 Bs[3][256 * 32];   // 48 KB
  const int tid = threadIdx.x;
  const int n = blockIdx.x;            // 0..767
  const int xcd = n & 7, j = n >> 3;   // j 0..95
  const int mb = xcd * 8 + (j & 7);    // 0..63
  const int nb2 = j >> 3;              // 0..11 (256-col tiles)
  const int chunk = nb2 >> 2;          // 0:Q 1:K 2:V
  const float* Af = (chunk == 0) ? Aq : (chunk == 1) ? Ak : Avv;
  const int wid = tid >> 6, lane = tid & 63;
  const int wr = wid >> 2, wc = wid & 3;   // 2 M-waves x 4 N-waves
  const int g = lane >> 4, l15 = lane & 15;
  f32x4 acc[4][4] = {};

  const int bsrc = ((lane & 3) ^ ((lane >> 3) & 3)) * 8;
  const u16* Bg = Bt + (size_t)(nb2 * 256 + 2 * wid * 16 + (lane >> 2)) * 1024 + bsrc;
  const float* Ap = Af + (size_t)(mb * 128 + (tid >> 2)) * 1024 + (tid & 3) * 8;
  const int arow = tid >> 2;
  const int acs = (((tid & 3) ^ ((tid >> 3) & 3))) * 8;
  const int swzr = (l15 >> 1) & 3;
  const int bofs0 = (2 * wid) * 512, bofs1 = (2 * wid + 1) * 512;

  // ---- prologue: A(k0); B kt0; B kt1; A(k1) prefetch; convert k0 -> As[0]
  float4 a00 = *(const float4*)(Ap);
  float4 a01 = *(const float4*)(Ap + 4);
  GLOAD16(Bg, &Bs[0][bofs0]);
  GLOAD16(Bg + (size_t)16 * 1024, &Bs[0][bofs1]);
  GLOAD16(Bg + 32, &Bs[1][bofs0]);
  GLOAD16(Bg + (size_t)16 * 1024 + 32, &Bs[1][bofs1]);
  float4 fc0 = *(const float4*)(Ap + 32);   // A data k1 (for step 1)
  float4 fc1 = *(const float4*)(Ap + 36);
  {
    uint4 u;
    u.x = pk2bf(a00.x, a00.y); u.y = pk2bf(a00.z, a00.w);
    u.z = pk2bf(a01.x, a01.y); u.w = pk2bf(a01.z, a01.w);
    *(uint4*)&As[0][arow * 32 + acs] = u;
  }
  // B kt0 must be done; B kt1 + A(k1) stay in flight
  asm volatile("s_waitcnt vmcnt(4) lgkmcnt(0)" ::: "memory");
  __builtin_amdgcn_s_barrier();

  float4 fn0, fn1;
#pragma unroll 2
  for (int kk = 0; kk < 32; ++kk) {
    const bool more2 = (kk + 2 < 32);
    // 1. A loads for kk+2 (oldest of this step's issues)
    if (more2) {
      const int kn2 = (kk + 2) * 32;
      fn0 = *(const float4*)(Ap + kn2);
      fn1 = *(const float4*)(Ap + kn2 + 4);
      // 2. B gloads for buf[(kk+2)%3]
      u16* bd = &Bs[(kk + 2) % 3][0];
      GLOAD16(Bg + kn2, bd + bofs0);
      GLOAD16(Bg + (size_t)16 * 1024 + kn2, bd + bofs1);
    }
    // 3. convert fc (A data for kk+1, loaded at step kk-1) -> As[(kk+1)&1]
    if (kk + 1 < 32) {
      uint4 u;
      u.x = pk2bf(fc0.x, fc0.y); u.y = pk2bf(fc0.z, fc0.w);
      u.z = pk2bf(fc1.x, fc1.y); u.w = pk2bf(fc1.z, fc1.w);
      *(uint4*)&As[(kk + 1) & 1][arow * 32 + acs] = u;
    }
    // 4. fragments + MFMA from As[kk&1], Bs[kk%3]
    const u16* AsB = &As[kk & 1][0];
    const u16* BsB = &Bs[kk % 3][0];
    bfrag a[4], b[4];
#pragma unroll
    for (int m = 0; m < 4; ++m)
      a[m] = __builtin_bit_cast(bfrag,
          *(const uint4*)&AsB[(wr * 64 + m * 16 + l15) * 32 + ((g ^ swzr)) * 8]);
#pragma unroll
    for (int nn = 0; nn < 4; ++nn)
      b[nn] = __builtin_bit_cast(bfrag,
          *(const uint4*)&BsB[(wc * 64 + nn * 16 + l15) * 32 + ((g ^ swzr)) * 8]);
    __builtin_amdgcn_s_setprio(1);
#pragma unroll
    for (int m = 0; m < 4; ++m)
#pragma unroll
      for (int nn = 0; nn < 4; ++nn)
        acc[m][nn] = __builtin_amdgcn_mfma_f32_16x16x32_bf16(a[m], b[nn], acc[m][nn], 0, 0, 0);
    __builtin_amdgcn_s_setprio(0);
    // 5. counted sync: keep this step's 4 prefetches in flight
    if (kk < 31) {
      if (more2)
        asm volatile("s_waitcnt vmcnt(4) lgkmcnt(0)" ::: "memory");
      else
        asm volatile("s_waitcnt vmcnt(0) lgkmcnt(0)" ::: "memory");
      __builtin_amdgcn_s_barrier();
    }
    fc0 = fn0; fc1 = fn1;
  }

  const int row0 = mb * 128 + wr * 64 + g * 4;
  const int ccL = (nb2 & 3) * 256 + wc * 64 + l15;
  const float* bias = (chunk == 0) ? bq : (chunk == 1) ? bk : bv;
  const float qs = (chunk == 0) ? 0.125f * 1.44269504f : 1.0f;  // log2 domain
#pragma unroll
  for (int m = 0; m < 4; ++m) {
#pragma unroll
    for (int nn = 0; nn < 4; ++nn) {
      const int row = row0 + m * 16;
      const int cc = ccL + nn * 16;
      const float bcv = bias[cc];
      if (chunk < 2) {
        u16* dst = (chunk == 0) ? Qb : Kb;
#pragma unroll
        for (int r = 0; r < 4; ++r)
          dst[(size_t)(row + r) * 1024 + cc] = f2bf((acc[m][nn][r] + bcv) * qs);
      } else {
        u16 w[4];
#pragma unroll
        for (int r = 0; r < 4; ++r) w[r] = f2bf(acc[m][nn][r] + bcv);
        const size_t dst =
            ((size_t)((row >> 11) * 16 + (cc >> 6)) * 64 + (cc & 63)) * 2048 + (row & 2047);
        *(uint2*)(Vt + dst) = *(const uint2*)w;
      }
    }
  }
}

// ---------------- O-projection GEMM (R13, unchanged)
__global__ __launch_bounds__(256) void gemm_o(const u16* __restrict__ Abf,
                                              const u16* __restrict__ Bt,
                                              const float* __restrict__ bo,
                                              float* __restrict__ Of) {
  __shared__ u16 As[2][128 * 32];
  __shared__ u16 Bs[2][128 * 32];
  const int tid = threadIdx.x;
  const int n = blockIdx.x;
  const int xcd = n & 7, j = n >> 3;
  const int mb = xcd * 8 + (j & 7);
  const int nb = j >> 3;
  const int wid = tid >> 6, lane = tid & 63;
  const int wr = wid >> 1, wc = wid & 1;
  const int g = lane >> 4, l15 = lane & 15;
  f32x4 acc[4][4] = {};

  const int bsrc = ((lane & 3) ^ ((lane >> 3) & 3)) * 8;
  const int swzr = (l15 >> 1) & 3;
  const u16* Bg = Bt + (size_t)(nb * 128 + 2 * wid * 16 + (lane >> 2)) * 1024 + bsrc;
  const u16* Ag = Abf + (size_t)(mb * 128 + 2 * wid * 16 + (lane >> 2)) * 1024 + bsrc;

#pragma unroll
  for (int c = 0; c < 2; ++c) {
    GLOAD16(Ag + (size_t)c * 16 * 1024, &As[0][2 * wid * 512 + c * 512]);
    GLOAD16(Bg + (size_t)c * 16 * 1024, &Bs[0][2 * wid * 512 + c * 512]);
  }
  __syncthreads();
  int cur = 0;
  for (int kk = 0; kk < 32; ++kk) {
    if (kk < 31) {
      const int kn = (kk + 1) * 32;
#pragma unroll
      for (int c = 0; c < 2; ++c) {
        GLOAD16(Ag + (size_t)c * 16 * 1024 + kn, &As[cur ^ 1][2 * wid * 512 + c * 512]);
        GLOAD16(Bg + (size_t)c * 16 * 1024 + kn, &Bs[cur ^ 1][2 * wid * 512 + c * 512]);
      }
    }
    bfrag a[4], b[4];
#pragma unroll
    for (int m = 0; m < 4; ++m)
      a[m] = __builtin_bit_cast(bfrag,
          *(const uint4*)&As[cur][(wr * 64 + m * 16 + l15) * 32 + ((g ^ swzr)) * 8]);
#pragma unroll
    for (int nn = 0; nn < 4; ++nn)
      b[nn] = __builtin_bit_cast(bfrag,
          *(const uint4*)&Bs[cur][(wc * 64 + nn * 16 + l15) * 32 + ((g ^ swzr)) * 8]);
    __builtin_amdgcn_s_setprio(1);
#pragma unroll
    for (int m = 0; m < 4; ++m)
#pragma unroll
      for (int nn = 0; nn < 4; ++nn)
        acc[m][nn] = __builtin_amdgcn_mfma_f32_16x16x32_bf16(a[m], b[nn], acc[m][nn], 0, 0, 0);
    __builtin_amdgcn_s_setprio(0);
    if (kk < 31) { __syncthreads(); cur ^= 1; }
  }

  const int row0 = mb * 128 + wr * 64 + g * 4;
  const int col0 = nb * 128 + wc * 64 + l15;
#pragma unroll
  for (int m = 0; m < 4; ++m)
#pragma unroll
    for (int nn = 0; nn < 4; ++nn) {
      const int row = row0 + m * 16, col = col0 + nn * 16;
      const float bcv = bo[col];
#pragma unroll
      for (int r = 0; r < 4; ++r)
        Of[(size_t)(row + r) * 1024 + col] = acc[m][nn][r] + bcv;
    }
}

// ---------------- fused causal flash attention — fixed-max softmax with
// single-instruction v_exp_f32 (base-2). Scores arrive in log2 domain. (R19)
__global__ __launch_bounds__(512) void attn_fused(const u16* __restrict__ Qb,
                                                  const u16* __restrict__ Kb,
                                                  const u16* __restrict__ Vtg,
                                                  u16* __restrict__ Ob) {
  __shared__ u16 KV[2][2][4096];
  const int tid = threadIdx.x;
  const int wid = tid >> 6, lane = tid & 63;
  const int g = lane >> 4, l15 = lane & 15;
  const int n = blockIdx.x;
  const int half = n >> 8, idx = n & 255;
  const int xcd = idx & 7;
  const int bh = xcd * 8 + ((idx >> 3) & 7);
  const int grp = idx >> 6;
  const int u = half ? grp : (7 - grp);
  const int t = u * 8 + wid;
  const int b = bh >> 4, h = bh & 15;
  const size_t baserow = (size_t)b * 2048;
  const u16* Qg = Qb + baserow * 1024 + h * 64;
  const u16* Kg = Kb + baserow * 1024 + h * 64;
  const u16* Vg = Vtg + (size_t)bh * 64 * 2048;
  u16* Og = Ob + baserow * 1024 + h * 64;

  const int q0 = t * 32;
  const int qrow = q0 + l15;
  const int mysteps = (q0 >> 6) + 1;
  const int smax = 4 * u + 4;
  const float M2 = 6.0f;

  const int sr = tid >> 3;
  const int scc = (tid & 7) ^ (sr & 7);
  const u16* Kst = Kg + (size_t)sr * 1024 + scc * 8;
  const u16* Vst = Vg + (size_t)sr * 2048 + scc * 8;

  bfrag qa[2][2];
#pragma unroll
  for (int qf = 0; qf < 2; ++qf)
#pragma unroll
    for (int kh = 0; kh < 2; ++kh)
      qa[qf][kh] = __builtin_bit_cast(bfrag,
          *(const uint4*)(Qg + (size_t)(q0 + qf * 16 + l15) * 1024 + kh * 32 + g * 8));

  f32x4 accT[2][4] = {};
  float Ll[2] = {0.f, 0.f};

  const int s0lane = ((g & 1) << 5) | l15;
  const int s1lane = s0lane + 16;
  const bool ghi = (g >= 2);
  const int swz = l15 & 7;

  GLOAD16(Kst, &KV[0][0][wid * 512]);
  GLOAD16(Vst, &KV[0][1][wid * 512]);
  __syncthreads();

  for (int s = 0; s < smax; ++s) {
    const int cb = s & 1;
    if (s + 1 < smax) {
      const size_t kn = (size_t)(s + 1) << 6;
      GLOAD16(Kst + kn * 1024, &KV[cb ^ 1][0][wid * 512]);
      GLOAD16(Vst + kn, &KV[cb ^ 1][1][wid * 512]);
    }
    if (s < mysteps) {
      const int kv0 = s << 6;
      const bool diag = (s == mysteps - 1);
      const u16* KB = &KV[cb][0][0];
      const u16* VB = &KV[cb][1][0];

      bfrag kb[2][4];
#pragma unroll
      for (int tt = 0; tt < 4; ++tt)
#pragma unroll
        for (int kh = 0; kh < 2; ++kh)
          kb[kh][tt] = __builtin_bit_cast(bfrag,
              *(const uint4*)&KB[(tt * 16 + l15) * 64 + (((kh << 2) | g) ^ swz) * 8]);

      f32x4 sc[2][4];
      __builtin_amdgcn_s_setprio(1);
#pragma unroll
      for (int qf = 0; qf < 2; ++qf)
#pragma unroll
        for (int tt = 0; tt < 4; ++tt) {
          f32x4 z = {0.f, 0.f, 0.f, 0.f};
          z = __builtin_amdgcn_mfma_f32_16x16x32_bf16(kb[0][tt], qa[qf][0], z, 0, 0, 0);
          z = __builtin_amdgcn_mfma_f32_16x16x32_bf16(kb[1][tt], qa[qf][1], z, 0, 0, 0);
          sc[qf][tt] = z;
        }
      __builtin_amdgcn_s_setprio(0);

      bfrag vb[2][4];
#pragma unroll
      for (int et = 0; et < 4; ++et)
#pragma unroll
        for (int kcb = 0; kcb < 2; ++kcb)
          vb[kcb][et] = __builtin_bit_cast(bfrag,
              *(const uint4*)&VB[(et * 16 + l15) * 64 + (((kcb << 2) | g) ^ swz) * 8]);

#pragma unroll
      for (int qf = 0; qf < 2; ++qf) {
        if (diag) {
          const int qq = qrow + qf * 16;
#pragma unroll
          for (int tt = 0; tt < 4; ++tt) {
            const int kvb = kv0 + tt * 16 + g * 4;
#pragma unroll
            for (int r = 0; r < 4; ++r)
              sc[qf][tt][r] = (kvb + r <= qq) ? sc[qf][tt][r] : -100.0f;
          }
        }
        uint32_t pk[4][2];
        float ss = 0.f;
#pragma unroll
        for (int tt = 0; tt < 4; ++tt) {
          float p0 = fexp2(sc[qf][tt][0] - M2);
          float p1 = fexp2(sc[qf][tt][1] - M2);
          float p2 = fexp2(sc[qf][tt][2] - M2);
          float p3 = fexp2(sc[qf][tt][3] - M2);
          ss += (p0 + p1) + (p2 + p3);
          pk[tt][0] = cvtpk(p0, p1);
          pk[tt][1] = cvtpk(p2, p3);
        }
        Ll[qf] += ss;
        __builtin_amdgcn_s_setprio(1);
#pragma unroll
        for (int kcb = 0; kcb < 2; ++kcb) {
          const int lo = kcb * 2, hi = kcb * 2 + 1;
          const uint32_t a0 = __shfl(pk[lo][0], s0lane), b0 = __shfl(pk[hi][0], s0lane);
          const uint32_t a1 = __shfl(pk[lo][1], s0lane), b1 = __shfl(pk[hi][1], s0lane);
          const uint32_t a2 = __shfl(pk[lo][0], s1lane), b2 = __shfl(pk[hi][0], s1lane);
          const uint32_t a3 = __shfl(pk[lo][1], s1lane), b3 = __shfl(pk[hi][1], s1lane);
          uint4 uu;
          uu.x = ghi ? b0 : a0; uu.y = ghi ? b1 : a1;
          uu.z = ghi ? b2 : a2; uu.w = ghi ? b3 : a3;
          const bfrag pfrag = __builtin_bit_cast(bfrag, uu);
#pragma unroll
          for (int et = 0; et < 4; ++et)
            accT[qf][et] = __builtin_amdgcn_mfma_f32_16x16x32_bf16(vb[kcb][et], pfrag, accT[qf][et], 0, 0, 0);
        }
        __builtin_amdgcn_s_setprio(0);
      }
    }
    __syncthreads();
  }

#pragma unroll
  for (int qf = 0; qf < 2; ++qf) {
    float Ls = Ll[qf];
    Ls += __shfl_xor(Ls, 16);
    Ls += __shfl_xor(Ls, 32);
    const float inv = 1.f / Ls;
    u16* orow = Og + (size_t)(q0 + qf * 16 + l15) * 1024 + g * 4;
#pragma unroll
    for (int et = 0; et < 4; ++et) {
      uint2 w;
      w.x = cvtpk(accT[qf][et][0] * inv, accT[qf][et][1] * inv);
      w.y = cvtpk(accT[qf][et][2] * inv, accT[qf][et][3] * inv);
      *(uint2*)(orow + et * 16) = w;
    }
  }
}

extern "C" void kernel_launch(void* const* d_in, const int* in_sizes, int n_in,
                              void* d_out, int out_size, void* d_ws, size_t ws_size,
                              hipStream_t stream) {
  const float* keys    = (const float*)d_in[0];
  const float* queries = (const float*)d_in[1];
  const float* values  = (const float*)d_in[2];
  const float* Wq = (const float*)d_in[3];
  const float* bq = (const float*)d_in[4];
  const float* Wk = (const float*)d_in[5];
  const float* bk = (const float*)d_in[6];
  const float* Wv = (const float*)d_in[7];
  const float* bv = (const float*)d_in[8];
  const float* Wo = (const float*)d_in[9];
  const float* bo = (const float*)d_in[10];
  float* out = (float*)d_out;

  char* ws = (char*)d_ws;
  const size_t MB = 1u << 20;
  u16* Wqkvt = (u16*)(ws);               // 0..6 MB
  u16* Wot   = (u16*)(ws + 6 * MB);      // 6..8 MB
  u16* Qb    = (u16*)(ws + 8 * MB);      // 8..24
  u16* Kb    = (u16*)(ws + 24 * MB);     // 24..40
  u16* Vtg   = (u16*)(ws + 40 * MB);     // 40..56
  u16* Ob    = (u16*)(ws + 56 * MB);     // 56..72

  const dim3 pg(16, 16);
  pack_w_hde<<<pg, 256, 0, stream>>>(Wq, Wqkvt);
  pack_w_hde<<<pg, 256, 0, stream>>>(Wk, Wqkvt + (size_t)1024 * 1024);
  pack_w_hde<<<pg, 256, 0, stream>>>(Wv, Wqkvt + (size_t)2048 * 1024);
  transpose_w<<<pg, 256, 0, stream>>>(Wo, Wot);

  gemm_qkv<<<dim3(768), 512, 0, stream>>>(queries, keys, values, Wqkvt,
                                          bq, bk, bv, Qb, Kb, Vtg);

  attn_fused<<<dim3(512), 512, 0, stream>>>(Qb, Kb, Vtg, Ob);

  gemm_o<<<dim3(512), 256, 0, stream>>>(Ob, Wot, bo, out);
}